// Round 3
// baseline (2784.404 us; speedup 1.0000x reference)
//
#include <hip/hip_runtime.h>
#include <math.h>

#define DEV __device__ __forceinline__

DEV float wredf(float v){
  v += __shfl_xor(v, 32, 64);
  v += __shfl_xor(v, 16, 64);
  v += __shfl_xor(v, 8, 64);
  v += __shfl_xor(v, 4, 64);
  v += __shfl_xor(v, 2, 64);
  v += __shfl_xor(v, 1, 64);
  return v;
}

// ---------------- h0: (B,3,256,256) -> (B,256,256,4) with time ----------------
__global__ void h0_kernel(const float* __restrict__ x, float* __restrict__ h0){
  int idx = blockIdx.x*256 + threadIdx.x;            // < 32*65536
  int b = idx >> 16, p = idx & 65535;
  const float* xb = x + (size_t)b*3*65536;
  float v0 = xb[p], v1 = xb[65536 + p], v2 = xb[131072 + p];
  float4 o;
  o.x = sqrtf(v0*v0 + v1*v1 + v2*v2 + 1.f);
  o.y = v0; o.z = v1; o.w = v2;
  *(float4*)&h0[(size_t)idx*4] = o;
}

// ---------------- conv GEMM: 64 pixels x 64 out-channels, K chunks of 32 -----
__global__ __launch_bounds__(256) void conv_kernel(
    const float* __restrict__ hin, const float* __restrict__ Wm,
    const float* __restrict__ bias, float* __restrict__ yout,
    int Hin, int Win, int Cin, int Ho, int Wo, int Cout, int K){
  __shared__ __align__(16) float A[32][64];
  __shared__ __align__(16) float Wb[32][64];
  int tid = threadIdx.x;
  int tilesX = Wo >> 3;
  int tile = blockIdx.x;
  int b = blockIdx.y;
  int zbase = blockIdx.z * 64;
  int oy0 = (tile / tilesX) * 8, ox0 = (tile % tilesX) * 8;
  int tx = tid & 15, ty = tid >> 4;
  float acc[4][4] = {};
  int nchunks = (K + 31) / 32;
  for (int ch = 0; ch < nchunks; ++ch){
    int k0 = ch * 32;
    for (int idx = tid; idx < 2048; idx += 256){
      int kk = idx >> 6, m = idx & 63;
      int k = k0 + kk;
      float v = 0.f;
      if (k > 0 && k < K){
        int t = k - 1; int c = t / 9; int kp = t - c*9;
        int py = oy0 + (m >> 3), px = ox0 + (m & 7);
        int iy = py*2 + kp/3 - 1;
        int ix = px*2 + (kp - (kp/3)*3) - 1;
        if ((unsigned)iy < (unsigned)Hin && (unsigned)ix < (unsigned)Win)
          v = hin[(((size_t)b*Hin + iy)*Win + ix)*Cin + 1 + c];
      }
      A[kk][m] = v;
    }
    if (k0 == 0 && tid < 64){
      int m = tid;
      int py = oy0 + (m >> 3), px = ox0 + (m & 7);
      float s = 0.f;
      for (int kp = 0; kp < 9; ++kp){
        int iy = py*2 + kp/3 - 1, ix = px*2 + kp%3 - 1;
        float tv = 1.f;  // zero-padded point clamps to sqrt(K)=1
        if ((unsigned)iy < (unsigned)Hin && (unsigned)ix < (unsigned)Win)
          tv = fmaxf(hin[(((size_t)b*Hin + iy)*Win + ix)*Cin], 1.f);
        s += tv*tv;
      }
      A[0][m] = sqrtf(fmaxf(s - 8.f, 0.f));
    }
    for (int idx = tid; idx < 2048; idx += 256){
      int kk = idx >> 6, n = idx & 63;
      int k = k0 + kk;
      int o = zbase + n + 1;
      Wb[kk][n] = (k < K && o < Cout) ? Wm[(size_t)o*K + k] : 0.f;
    }
    __syncthreads();
    #pragma unroll
    for (int kk = 0; kk < 32; ++kk){
      float4 a4 = *(const float4*)&A[kk][tx*4];
      float4 w4 = *(const float4*)&Wb[kk][ty*4];
      float av[4] = {a4.x, a4.y, a4.z, a4.w};
      float wv[4] = {w4.x, w4.y, w4.z, w4.w};
      #pragma unroll
      for (int i = 0; i < 4; ++i)
        #pragma unroll
        for (int j = 0; j < 4; ++j)
          acc[i][j] = fmaf(av[i], wv[j], acc[i][j]);
    }
    __syncthreads();
  }
  #pragma unroll
  for (int j = 0; j < 4; ++j){
    int o = zbase + ty*4 + j + 1;
    if (o < Cout){
      float bv = bias[o];
      #pragma unroll
      for (int i = 0; i < 4; ++i){
        int m = tx*4 + i;
        int py = oy0 + (m >> 3), px = ox0 + (m & 7);
        yout[(((size_t)b*Ho + py)*Wo + px)*Cout + o] = acc[i][j] + bv;
      }
    }
  }
}

// ---------------- time (thread-per-point): y[p][0] = sqrt(sum space^2 + 1) --
template<int C>
__global__ void time_t_kernel(float* __restrict__ y, int P){
  int p = blockIdx.x*256 + threadIdx.x;
  if (p >= P) return;
  float* yp = y + (size_t)p * C;
  float ss = 0.f;
  #pragma unroll
  for (int c = 1; c < C; ++c){ float v = yp[c]; ss = fmaf(v, v, ss); }
  yp[0] = sqrtf(ss + 1.f);
}

// ---------------- per-(b,blk,c) partial channel sums (no atomics) -----------
__global__ void rsum_part_kernel(const float* __restrict__ y, float* __restrict__ red2,
                                 int N, int C, int BPB){
  int b = blockIdx.y, blk = blockIdx.x;
  int chunk = N / BPB;
  int n0 = blk*chunk, n1 = n0 + chunk;
  int tid = threadIdx.x;
  float a0 = 0.f, a1 = 0.f;
  for (int n = n0; n < n1; ++n){
    const float* yp = y + ((size_t)b*N + n) * C;
    if (tid < C) a0 += yp[tid];
    if (tid + 256 < C) a1 += yp[tid + 256];
  }
  float* rp = red2 + ((size_t)b*BPB + blk) * C;
  if (tid < C) rp[tid] = a0;
  if (tid + 256 < C) rp[tid + 256] = a1;
}

// ---------------- double centroid -> mean vector; zero scratch scalars ------
__global__ void bn_stats_kernel(const float* __restrict__ red2, float* __restrict__ mean,
                                float* __restrict__ scal, int B, int N, int C, int BPB){
  __shared__ float s[256];
  int tid = threadIdx.x;
  float acc2a = 0.f, acc2b = 0.f;
  for (int b = 0; b < B; ++b){
    float va = 0.f, vb = 0.f;
    for (int blk = 0; blk < BPB; ++blk){
      const float* rp = red2 + ((size_t)b*BPB + blk) * C;
      if (tid < C) va += rp[tid];
      if (tid + 256 < C) vb += rp[tid + 256];
    }
    va /= (float)N; vb /= (float)N;
    float pr = ((tid == 0) ? -va*va : va*va) + vb*vb;   // Minkowski <avg,avg>
    s[tid] = pr; __syncthreads();
    for (int st = 128; st; st >>= 1){ if (tid < st) s[tid] += s[tid+st]; __syncthreads(); }
    float lo = s[0]; __syncthreads();
    float den = sqrtf(fmaxf(fabsf(lo), 1e-8f));
    acc2a += va / den; acc2b += vb / den;
  }
  acc2a /= (float)B; acc2b /= (float)B;
  float pr = ((tid == 0) ? -acc2a*acc2a : acc2a*acc2a) + acc2b*acc2b;
  s[tid] = pr; __syncthreads();
  for (int st = 128; st; st >>= 1){ if (tid < st) s[tid] += s[tid+st]; __syncthreads(); }
  float den2 = sqrtf(fmaxf(fabsf(s[0]), 1e-8f));
  if (tid < C) mean[tid] = acc2a / den2;
  if (tid + 256 < C) mean[tid + 256] = acc2b / den2;
  if (tid < 40) scal[tid] = 0.f;   // var accumulator + flatten square-sums
}

// ---------------- Frechet variance, thread-per-point ------------------------
template<int C>
__global__ __launch_bounds__(256) void bn_var_t_kernel(const float* __restrict__ y,
    const float* __restrict__ mean, float* __restrict__ scal, int P){
  __shared__ float sm[C];
  __shared__ float part[4];
  for (int i = threadIdx.x; i < C; i += 256) sm[i] = mean[i];
  __syncthreads();
  float acc = 0.f;
  int stride = gridDim.x * 256;
  for (int p = blockIdx.x*256 + threadIdx.x; p < P; p += stride){
    const float* yp = y + (size_t)p * C;
    float a[C];
    float d1 = 0.f;
    #pragma unroll
    for (int c = 0; c < C; ++c){
      a[c] = yp[c];
      float pr = a[c]*sm[c];
      d1 += (c == 0) ? -pr : pr;
    }
    float xy = d1;
    float dist = acoshf(fmaxf(-xy, 1.f + 1e-7f));
    float d2 = 0.f;
    #pragma unroll
    for (int c = 0; c < C; ++c){
      a[c] = fmaf(xy, sm[c], a[c]);
      float pr = a[c]*a[c];
      d2 += (c == 0) ? -pr : pr;
    }
    float den = sqrtf(fmaxf(d2, 1e-8f));
    float sc = dist / den;
    float corr = -(a[0]*sc) / (1.f + sm[0]);
    float ns = 0.f;
    #pragma unroll
    for (int c = 0; c < C; ++c){
      float uc = fmaf(corr, sm[c] + ((c == 0) ? 1.f : 0.f), a[c]*sc);
      ns = fmaf(uc, uc, ns);
    }
    acc += sqrtf(ns);
  }
  acc = wredf(acc);
  if ((threadIdx.x & 63) == 0) part[threadIdx.x >> 6] = acc;
  __syncthreads();
  if (threadIdx.x == 0)
    atomicAdd(scal, part[0] + part[1] + part[2] + part[3]);
}

// ---------------- BN apply, thread-per-point --------------------------------
template<int C>
__global__ __launch_bounds__(256) void bn_apply_t_kernel(const float* __restrict__ y,
    const float* __restrict__ mean, const float* __restrict__ beta,
    const float* __restrict__ gamma, const float* __restrict__ scal,
    float* __restrict__ hout, int P){
  __shared__ float sm[C];
  __shared__ float sb[C];
  for (int i = threadIdx.x; i < C; i += 256){ sm[i] = mean[i]; sb[i] = beta[i]; }
  __syncthreads();
  int p = blockIdx.x*256 + threadIdx.x;
  if (p >= P) return;
  const float* yp = y + (size_t)p * C;
  float a[C];
  float d1 = 0.f;
  #pragma unroll
  for (int c = 0; c < C; ++c){
    a[c] = yp[c];
    float pr = a[c]*sm[c];
    d1 += (c == 0) ? -pr : pr;
  }
  float xy = d1;
  float dist = acoshf(fmaxf(-xy, 1.f + 1e-7f));
  float d2 = 0.f;
  #pragma unroll
  for (int c = 0; c < C; ++c){
    a[c] = fmaf(xy, sm[c], a[c]);
    float pr = a[c]*a[c];
    d2 += (c == 0) ? -pr : pr;
  }
  float den = sqrtf(fmaxf(d2, 1e-8f));
  float sc = dist / den;
  float corr = -(a[0]*sc) / (1.f + sm[0]);
  float var = scal[0] / (float)P;
  float g = gamma[0] / (var + 1e-5f);
  #pragma unroll
  for (int c = 0; c < C; ++c)
    a[c] = fmaf(corr, sm[c] + ((c == 0) ? 1.f : 0.f), a[c]*sc) * g;
  float d3 = 0.f;
  #pragma unroll
  for (int c = 0; c < C; ++c){
    float pr = a[c]*sb[c];
    d3 += (c == 0) ? -pr : pr;
  }
  float cb = d3 / (1.f + sb[0]);
  float d4 = 0.f;
  #pragma unroll
  for (int c = 0; c < C; ++c){
    a[c] = fmaf(cb, sb[c] + ((c == 0) ? 1.f : 0.f), a[c]);
    float pr = a[c]*a[c];
    d4 += (c == 0) ? -pr : pr;
  }
  float nu = sqrtf(fmaxf(d4, 1e-8f));
  float ch = coshf(nu), shn = sinhf(nu) / nu;
  float* hp = hout + (size_t)p * C;
  float ssum = 0.f;
  #pragma unroll
  for (int c = 1; c < C; ++c){
    float r = fmaxf(fmaf(ch, sb[c], shn*a[c]), 0.f);
    hp[c] = r;
    ssum = fmaf(r, r, ssum);
  }
  hp[0] = sqrtf(ssum + 1.f);
}

// ---------------- L3 (C=257) wave-per-point fallbacks -----------------------
__global__ void bn_var_kernel(const float* __restrict__ y, const float* __restrict__ mean,
                              float* __restrict__ scal, int P, int C){
  __shared__ float smean[260];
  __shared__ float part[4];
  for (int i = threadIdx.x; i < C; i += blockDim.x) smean[i] = mean[i];
  __syncthreads();
  int wv = threadIdx.x >> 6, lane = threadIdx.x & 63;
  int nwaves = gridDim.x * 4;
  float m0 = smean[0];
  float ms[5];
  #pragma unroll
  for (int j = 0; j < 5; ++j){
    int c = lane + 64*j;
    ms[j] = (c < C) ? smean[c] : 0.f;
  }
  float vsum = 0.f;
  for (int p = blockIdx.x*4 + wv; p < P; p += nwaves){
    const float* yp = y + (size_t)p * C;
    float yv[5], nom[5];
    #pragma unroll
    for (int j = 0; j < 5; ++j){
      int c = lane + 64*j;
      yv[j] = (c < C) ? yp[c] : 0.f;
    }
    float d1 = 0.f;
    #pragma unroll
    for (int j = 0; j < 5; ++j){
      int c = lane + 64*j;
      float prd = yv[j]*ms[j];
      d1 += (c == 0) ? -prd : prd;
    }
    float xy = wredf(d1);
    float dist = acoshf(fmaxf(-xy, 1.f + 1e-7f));
    float d2 = 0.f;
    #pragma unroll
    for (int j = 0; j < 5; ++j){
      int c = lane + 64*j;
      nom[j] = yv[j] + xy*ms[j];
      float prd = nom[j]*nom[j];
      d2 += (c == 0) ? -prd : prd;
    }
    float den = sqrtf(fmaxf(wredf(d2), 1e-8f));
    float sc = dist / den;
    float u0 = __shfl(nom[0], 0, 64) * sc;
    float corr = -u0 / (1.f + m0);
    float nsum = 0.f;
    #pragma unroll
    for (int j = 0; j < 5; ++j){
      int c = lane + 64*j;
      float uc = nom[j]*sc + corr*(ms[j] + ((c == 0) ? 1.f : 0.f));
      nsum += uc*uc;
    }
    nsum = wredf(nsum);
    vsum += sqrtf(nsum);
  }
  if (lane == 0) part[wv] = vsum;
  __syncthreads();
  if (threadIdx.x == 0)
    atomicAdd(scal, part[0] + part[1] + part[2] + part[3]);
}

__global__ void bn_apply_kernel(const float* __restrict__ y, const float* __restrict__ mean,
                                const float* __restrict__ beta, const float* __restrict__ gamma,
                                const float* __restrict__ scal, float* __restrict__ hout,
                                int P, int C){
  __shared__ float smean[260];
  __shared__ float sbeta[260];
  for (int i = threadIdx.x; i < C; i += blockDim.x){ smean[i] = mean[i]; sbeta[i] = beta[i]; }
  __syncthreads();
  int wv = threadIdx.x >> 6, lane = threadIdx.x & 63;
  int p = blockIdx.x*4 + wv;
  if (p >= P) return;
  const float* yp = y + (size_t)p * C;
  float yv[5], ms[5], bs[5], nom[5], uc[5], u2[5];
  #pragma unroll
  for (int j = 0; j < 5; ++j){
    int c = lane + 64*j;
    yv[j] = (c < C) ? yp[c] : 0.f;
    ms[j] = (c < C) ? smean[c] : 0.f;
    bs[j] = (c < C) ? sbeta[c] : 0.f;
  }
  float m0 = smean[0], b0 = sbeta[0];
  float d1 = 0.f;
  #pragma unroll
  for (int j = 0; j < 5; ++j){
    int c = lane + 64*j;
    float prd = yv[j]*ms[j];
    d1 += (c == 0) ? -prd : prd;
  }
  float xy = wredf(d1);
  float dist = acoshf(fmaxf(-xy, 1.f + 1e-7f));
  float d2 = 0.f;
  #pragma unroll
  for (int j = 0; j < 5; ++j){
    nom[j] = yv[j] + xy*ms[j];
    int c = lane + 64*j;
    float prd = nom[j]*nom[j];
    d2 += (c == 0) ? -prd : prd;
  }
  float den = sqrtf(fmaxf(wredf(d2), 1e-8f));
  float sc = dist / den;
  float u0 = __shfl(nom[0], 0, 64) * sc;
  float corr = -u0 / (1.f + m0);
  float var = scal[0] / (float)P;
  float g = gamma[0] / (var + 1e-5f);
  #pragma unroll
  for (int j = 0; j < 5; ++j){
    int c = lane + 64*j;
    uc[j] = (nom[j]*sc + corr*(ms[j] + ((c == 0) ? 1.f : 0.f))) * g;
  }
  float d3 = 0.f;
  #pragma unroll
  for (int j = 0; j < 5; ++j){
    int c = lane + 64*j;
    float prd = uc[j]*bs[j];
    d3 += (c == 0) ? -prd : prd;
  }
  float cb = wredf(d3) / (1.f + b0);
  float d4 = 0.f;
  #pragma unroll
  for (int j = 0; j < 5; ++j){
    int c = lane + 64*j;
    u2[j] = uc[j] + cb*(bs[j] + ((c == 0) ? 1.f : 0.f));
    float prd = u2[j]*u2[j];
    d4 += (c == 0) ? -prd : prd;
  }
  float nu = sqrtf(fmaxf(wredf(d4), 1e-8f));
  float ch = coshf(nu), shn = sinhf(nu) / nu;
  float ssum = 0.f;
  float* hp = hout + (size_t)p * C;
  #pragma unroll
  for (int j = 0; j < 5; ++j){
    int c = lane + 64*j;
    if (c > 0 && c < C){
      float r = ch*sbeta[c] + shn*u2[j];
      r = fmaxf(r, 0.f);
      hp[c] = r;
      ssum += r*r;
    }
  }
  ssum = wredf(ssum);
  if (lane == 0) hp[0] = sqrtf(ssum + 1.f);
}

// ---------------- flatten h4 (B,256,257) -> (B,65537) + square sums ---------
__global__ void flatten_kernel(const float* __restrict__ h, float* __restrict__ flat,
                               float* __restrict__ scal){
  __shared__ float s[256];
  int tid = threadIdx.x;
  int idx = blockIdx.x*256 + tid;
  int b = idx >> 16, r = idx & 65535;
  int n = r >> 8, c = r & 255;
  float v = h[(((size_t)b << 8) + n)*257 + 1 + c];
  flat[(size_t)b*65537 + 1 + r] = v;
  s[tid] = v*v; __syncthreads();
  for (int st = 128; st; st >>= 1){ if (tid < st) s[tid] += s[tid+st]; __syncthreads(); }
  if (tid == 0) atomicAdd(&scal[1 + b], s[0]);
}

__global__ void flat_time_kernel(float* __restrict__ flat, const float* __restrict__ scal){
  int b = threadIdx.x;
  if (b < 32) flat[(size_t)b*65537] = sqrtf(scal[1 + b] + 1.f);
}

// ---------------- head GEMM: split-K, h in LDS, W streamed ------------------
__global__ __launch_bounds__(256) void fgemm_kernel(const float* __restrict__ flat,
    const float* __restrict__ wm, const float* __restrict__ wv,
    float* __restrict__ mvacc){
  __shared__ float hch[256*33];
  int tid = threadIdx.x;
  int k0 = blockIdx.x * 256;
  int obase = blockIdx.y * 32;
  {
    int k = k0 + tid;
    for (int b2 = 0; b2 < 32; ++b2){
      float v = (k < 65537) ? flat[(size_t)b2*65537 + k] : 0.f;
      hch[tid*33 + b2] = v;
    }
  }
  __syncthreads();
  int b = tid & 31, os = tid >> 5;
  const float* rows[4];
  float accv[4] = {0.f, 0.f, 0.f, 0.f};
  #pragma unroll
  for (int r = 0; r < 4; ++r){
    int o = obase + os + r*8;
    rows[r] = (o < 512) ? (wm + (size_t)(o + 1)*65537) : (wv + (size_t)(o - 511)*65537);
  }
  int kRem = min(256, 65537 - k0);
  int k4 = kRem & ~3;
  for (int k = 0; k < k4; k += 4){
    float h0 = hch[(k+0)*33 + b], h1 = hch[(k+1)*33 + b];
    float h2 = hch[(k+2)*33 + b], h3 = hch[(k+3)*33 + b];
    #pragma unroll
    for (int r = 0; r < 4; ++r){
      const float* rw = rows[r] + k0 + k;
      accv[r] += h0*rw[0] + h1*rw[1] + h2*rw[2] + h3*rw[3];
    }
  }
  for (int k = k4; k < kRem; ++k){
    float hv = hch[k*33 + b];
    #pragma unroll
    for (int r = 0; r < 4; ++r) accv[r] += hv * rows[r][k0 + k];
  }
  #pragma unroll
  for (int r = 0; r < 4; ++r){
    int o = obase + os + r*8;
    atomicAdd(&mvacc[o*32 + b], accv[r]);
  }
}

// ---------------- finalize: bias, time, softplus ----------------------------
__global__ void finalize_kernel(const float* __restrict__ mvacc, const float* __restrict__ bm,
                                const float* __restrict__ bv, float* __restrict__ out){
  __shared__ float s[256];
  int b = blockIdx.x, tid = threadIdx.x;
  float m0 = mvacc[tid*32 + b] + bm[tid + 1];
  float m1 = mvacc[(tid + 256)*32 + b] + bm[tid + 257];
  s[tid] = m0*m0 + m1*m1; __syncthreads();
  for (int st = 128; st; st >>= 1){ if (tid < st) s[tid] += s[tid+st]; __syncthreads(); }
  float t = sqrtf(s[0] + 1.f);
  float* om = out + (size_t)b*513;
  om[1 + tid] = m0;
  om[1 + tid + 256] = m1;
  if (tid == 0) om[0] = t;
  float v0 = mvacc[(512 + tid)*32 + b] + bv[tid + 1];
  float v1 = mvacc[(512 + tid + 256)*32 + b] + bv[tid + 257];
  float sp0 = fmaxf(v0, 0.f) + log1pf(expf(-fabsf(v0)));
  float sp1 = fmaxf(v1, 0.f) + log1pf(expf(-fabsf(v1)));
  float* ov = out + 32*513 + (size_t)b*512;
  ov[tid] = fmaxf(sp0, 1e-5f);
  ov[tid + 256] = fmaxf(sp1, 1e-5f);
}

extern "C" void kernel_launch(void* const* d_in, const int* in_sizes, int n_in,
                              void* d_out, int out_size, void* d_ws, size_t ws_size,
                              hipStream_t stream){
  const float* x  = (const float*)d_in[0];
  const float* cw[4] = {(const float*)d_in[1], (const float*)d_in[5], (const float*)d_in[9],  (const float*)d_in[13]};
  const float* cb[4] = {(const float*)d_in[2], (const float*)d_in[6], (const float*)d_in[10], (const float*)d_in[14]};
  const float* bb[4] = {(const float*)d_in[3], (const float*)d_in[7], (const float*)d_in[11], (const float*)d_in[15]};
  const float* bg[4] = {(const float*)d_in[4], (const float*)d_in[8], (const float*)d_in[12], (const float*)d_in[16]};
  const float* wm = (const float*)d_in[17];
  const float* bm = (const float*)d_in[18];
  const float* wv = (const float*)d_in[19];
  const float* bv = (const float*)d_in[20];
  float* ws = (float*)d_ws;

  // workspace layout (floats)
  float* S[3] = { ws, ws + 9000000, ws + 26400000 };      // 9M / 17.4M / 17.4M
  // red2 lives in S1's tail slack: only layer-0 y/hout use >17.30M of S1's 17.4M
  float* red2  = ws + 26302000;                           // <= 68k floats
  float* meanp = ws + 43810000;                           // up to 257
  float* scal  = ws + 43811000;                           // [0]=var sum, [1..32]=flat sq
  float* mvacc = ws + 43812000;                           // 1024*32

  hipMemsetAsync(mvacc, 0, 32768*sizeof(float), stream);

  h0_kernel<<<8192, 256, 0, stream>>>(x, S[0]);

  const int HinA[4]  = {256, 128, 64, 32};
  const int SinA[4]  = {3, 32, 64, 128};
  const int HoA[4]   = {128, 64, 32, 16};
  const int CoutA[4] = {33, 65, 129, 257};
  const int KA[4]    = {28, 289, 577, 1153};
  const int BPBA[4]  = {64, 32, 16, 8};

  int cur = 0;
  for (int i = 0; i < 4; ++i){
    int Hin = HinA[i], Win = HinA[i], Cin = SinA[i] + 1;
    int Ho = HoA[i], Wo = HoA[i], Cout = CoutA[i], K = KA[i];
    int BPB = BPBA[i];
    float* hin  = S[cur];
    float* y    = S[(cur + 1) % 3];
    float* hout = S[(cur + 2) % 3];
    int tiles = (Ho/8) * (Wo/8);
    dim3 g(tiles, 32, (Cout - 1 + 63)/64);
    conv_kernel<<<g, 256, 0, stream>>>(hin, cw[i], cb[i], y, Hin, Win, Cin, Ho, Wo, Cout, K);
    int N = Ho * Wo;
    int P = 32 * N;
    int pb = P / 256;                       // P is always a multiple of 256
    switch (i){
      case 0: time_t_kernel<33><<<pb, 256, 0, stream>>>(y, P); break;
      case 1: time_t_kernel<65><<<pb, 256, 0, stream>>>(y, P); break;
      case 2: time_t_kernel<129><<<pb, 256, 0, stream>>>(y, P); break;
      case 3: time_t_kernel<257><<<pb, 256, 0, stream>>>(y, P); break;
    }
    rsum_part_kernel<<<dim3(BPB, 32), 256, 0, stream>>>(y, red2, N, Cout, BPB);
    bn_stats_kernel<<<1, 256, 0, stream>>>(red2, meanp, scal, 32, N, Cout, BPB);
    int vb = min(pb, 2048);
    switch (i){
      case 0:
        bn_var_t_kernel<33><<<vb, 256, 0, stream>>>(y, meanp, scal, P);
        bn_apply_t_kernel<33><<<pb, 256, 0, stream>>>(y, meanp, bb[i], bg[i], scal, hout, P);
        break;
      case 1:
        bn_var_t_kernel<65><<<vb, 256, 0, stream>>>(y, meanp, scal, P);
        bn_apply_t_kernel<65><<<pb, 256, 0, stream>>>(y, meanp, bb[i], bg[i], scal, hout, P);
        break;
      case 2:
        bn_var_t_kernel<129><<<vb, 256, 0, stream>>>(y, meanp, scal, P);
        bn_apply_t_kernel<129><<<pb, 256, 0, stream>>>(y, meanp, bb[i], bg[i], scal, hout, P);
        break;
      case 3:
        bn_var_kernel<<<min((P + 3)/4, 2048), 256, 0, stream>>>(y, meanp, scal, P, Cout);
        bn_apply_kernel<<<(P + 3)/4, 256, 0, stream>>>(y, meanp, bb[i], bg[i], scal, hout, P, Cout);
        break;
    }
    cur = (cur + 2) % 3;
  }

  // h4 now in S[cur] (== S[2]); flatten into S[0]
  float* flatp = S[0];
  flatten_kernel<<<8192, 256, 0, stream>>>(S[cur], flatp, scal);
  flat_time_kernel<<<1, 64, 0, stream>>>(flatp, scal);
  fgemm_kernel<<<dim3(257, 32), 256, 0, stream>>>(flatp, wm, wv, mvacc);
  finalize_kernel<<<32, 256, 0, stream>>>(mvacc, bm, bv, (float*)d_out);
}

// Round 4
// 1721.860 us; speedup vs baseline: 1.6171x; 1.6171x over previous
//
#include <hip/hip_runtime.h>
#include <math.h>

#define DEV __device__ __forceinline__

DEV float wredf(float v){
  v += __shfl_xor(v, 32, 64);
  v += __shfl_xor(v, 16, 64);
  v += __shfl_xor(v, 8, 64);
  v += __shfl_xor(v, 4, 64);
  v += __shfl_xor(v, 2, 64);
  v += __shfl_xor(v, 1, 64);
  return v;
}

// ---------------- h0: (B,3,256,256) -> (B,256,256,4) with time ----------------
__global__ void h0_kernel(const float* __restrict__ x, float* __restrict__ h0){
  int idx = blockIdx.x*256 + threadIdx.x;            // < 32*65536
  int b = idx >> 16, p = idx & 65535;
  const float* xb = x + (size_t)b*3*65536;
  float v0 = xb[p], v1 = xb[65536 + p], v2 = xb[131072 + p];
  float4 o;
  o.x = sqrtf(v0*v0 + v1*v1 + v2*v2 + 1.f);
  o.y = v0; o.z = v1; o.w = v2;
  *(float4*)&h0[(size_t)idx*4] = o;
}

// ---------------- conv GEMM: 64 pixels x 64 out-channels, K chunks of 32 -----
__global__ __launch_bounds__(256) void conv_kernel(
    const float* __restrict__ hin, const float* __restrict__ Wm,
    const float* __restrict__ bias, float* __restrict__ yout,
    int Hin, int Win, int Cin, int Ho, int Wo, int Cout, int K){
  __shared__ __align__(16) float A[32][64];
  __shared__ __align__(16) float Wb[32][64];
  int tid = threadIdx.x;
  int tilesX = Wo >> 3;
  int tile = blockIdx.x;
  int b = blockIdx.y;
  int zbase = blockIdx.z * 64;
  int oy0 = (tile / tilesX) * 8, ox0 = (tile % tilesX) * 8;
  int tx = tid & 15, ty = tid >> 4;
  float acc[4][4] = {};
  int nchunks = (K + 31) / 32;
  for (int ch = 0; ch < nchunks; ++ch){
    int k0 = ch * 32;
    for (int idx = tid; idx < 2048; idx += 256){
      int kk = idx >> 6, m = idx & 63;
      int k = k0 + kk;
      float v = 0.f;
      if (k > 0 && k < K){
        int t = k - 1; int c = t / 9; int kp = t - c*9;
        int py = oy0 + (m >> 3), px = ox0 + (m & 7);
        int iy = py*2 + kp/3 - 1;
        int ix = px*2 + (kp - (kp/3)*3) - 1;
        if ((unsigned)iy < (unsigned)Hin && (unsigned)ix < (unsigned)Win)
          v = hin[(((size_t)b*Hin + iy)*Win + ix)*Cin + 1 + c];
      }
      A[kk][m] = v;
    }
    if (k0 == 0 && tid < 64){
      int m = tid;
      int py = oy0 + (m >> 3), px = ox0 + (m & 7);
      float s = 0.f;
      for (int kp = 0; kp < 9; ++kp){
        int iy = py*2 + kp/3 - 1, ix = px*2 + kp%3 - 1;
        float tv = 1.f;  // zero-padded point clamps to sqrt(K)=1
        if ((unsigned)iy < (unsigned)Hin && (unsigned)ix < (unsigned)Win)
          tv = fmaxf(hin[(((size_t)b*Hin + iy)*Win + ix)*Cin], 1.f);
        s += tv*tv;
      }
      A[0][m] = sqrtf(fmaxf(s - 8.f, 0.f));
    }
    for (int idx = tid; idx < 2048; idx += 256){
      int kk = idx >> 6, n = idx & 63;
      int k = k0 + kk;
      int o = zbase + n + 1;
      Wb[kk][n] = (k < K && o < Cout) ? Wm[(size_t)o*K + k] : 0.f;
    }
    __syncthreads();
    #pragma unroll
    for (int kk = 0; kk < 32; ++kk){
      float4 a4 = *(const float4*)&A[kk][tx*4];
      float4 w4 = *(const float4*)&Wb[kk][ty*4];
      float av[4] = {a4.x, a4.y, a4.z, a4.w};
      float wv[4] = {w4.x, w4.y, w4.z, w4.w};
      #pragma unroll
      for (int i = 0; i < 4; ++i)
        #pragma unroll
        for (int j = 0; j < 4; ++j)
          acc[i][j] = fmaf(av[i], wv[j], acc[i][j]);
    }
    __syncthreads();
  }
  #pragma unroll
  for (int j = 0; j < 4; ++j){
    int o = zbase + ty*4 + j + 1;
    if (o < Cout){
      float bv = bias[o];
      #pragma unroll
      for (int i = 0; i < 4; ++i){
        int m = tx*4 + i;
        int py = oy0 + (m >> 3), px = ox0 + (m & 7);
        yout[(((size_t)b*Ho + py)*Wo + px)*Cout + o] = acc[i][j] + bv;
      }
    }
  }
}

// ---------------- time (thread-per-point): y[p][0] = sqrt(sum space^2 + 1) --
template<int C>
__global__ void time_t_kernel(float* __restrict__ y, int P){
  int p = blockIdx.x*256 + threadIdx.x;
  if (p >= P) return;
  float* yp = y + (size_t)p * C;
  float ss = 0.f;
  #pragma unroll
  for (int c = 1; c < C; ++c){ float v = yp[c]; ss = fmaf(v, v, ss); }
  yp[0] = sqrtf(ss + 1.f);
}

// ---------------- per-(b,blk,c) partial channel sums (no atomics) -----------
__global__ void rsum_part_kernel(const float* __restrict__ y, float* __restrict__ red2,
                                 int N, int C, int BPB){
  int b = blockIdx.y, blk = blockIdx.x;
  int chunk = N / BPB;
  int n0 = blk*chunk, n1 = n0 + chunk;
  int tid = threadIdx.x;
  float a0 = 0.f, a1 = 0.f;
  for (int n = n0; n < n1; ++n){
    const float* yp = y + ((size_t)b*N + n) * C;
    if (tid < C) a0 += yp[tid];
    if (tid + 256 < C) a1 += yp[tid + 256];
  }
  float* rp = red2 + ((size_t)b*BPB + blk) * C;
  if (tid < C) rp[tid] = a0;
  if (tid + 256 < C) rp[tid + 256] = a1;
}

// ---------------- stage 1: per-b centroid (32 blocks, chain-broken loads) ----
__global__ void cent1_kernel(const float* __restrict__ red2, float* __restrict__ cent1,
                             int N, int C, int BPB){
  __shared__ float s[256];
  int b = blockIdx.x, tid = threadIdx.x;
  float a0=0.f,a1=0.f,a2=0.f,a3=0.f, c0=0.f,c1=0.f,c2=0.f,c3=0.f;
  for (int blk = 0; blk < BPB; blk += 4){
    const float* r0 = red2 + ((size_t)b*BPB + blk) * C;
    const float* r1 = r0 + C;
    const float* r2 = r0 + 2*(size_t)C;
    const float* r3 = r0 + 3*(size_t)C;
    if (tid < C){ a0 += r0[tid]; a1 += r1[tid]; a2 += r2[tid]; a3 += r3[tid]; }
    if (tid + 256 < C){
      c0 += r0[tid+256]; c1 += r1[tid+256]; c2 += r2[tid+256]; c3 += r3[tid+256];
    }
  }
  float va = ((a0+a1)+(a2+a3)) / (float)N;
  float vb = ((c0+c1)+(c2+c3)) / (float)N;
  float pr = ((tid == 0) ? -va*va : va*va) + vb*vb;   // Minkowski <avg,avg>
  s[tid] = pr; __syncthreads();
  for (int st = 128; st; st >>= 1){ if (tid < st) s[tid] += s[tid+st]; __syncthreads(); }
  float den = sqrtf(fmaxf(fabsf(s[0]), 1e-8f));
  if (tid < C) cent1[(size_t)b*C + tid] = va / den;
  if (tid + 256 < C) cent1[(size_t)b*C + tid + 256] = vb / den;
}

// ---------------- stage 2: centroid of centroids; zero scratch scalars ------
__global__ void stats2_kernel(const float* __restrict__ cent1, float* __restrict__ mean,
                              float* __restrict__ scal, int C){
  __shared__ float s[256];
  int tid = threadIdx.x;
  float a0=0.f,a1=0.f,a2=0.f,a3=0.f, c0=0.f,c1=0.f,c2=0.f,c3=0.f;
  #pragma unroll
  for (int b = 0; b < 32; b += 4){
    const float* r0 = cent1 + (size_t)b*C;
    const float* r1 = r0 + C;
    const float* r2 = r0 + 2*(size_t)C;
    const float* r3 = r0 + 3*(size_t)C;
    if (tid < C){ a0 += r0[tid]; a1 += r1[tid]; a2 += r2[tid]; a3 += r3[tid]; }
    if (tid + 256 < C){
      c0 += r0[tid+256]; c1 += r1[tid+256]; c2 += r2[tid+256]; c3 += r3[tid+256];
    }
  }
  float va = ((a0+a1)+(a2+a3)) * 0.03125f;
  float vb = ((c0+c1)+(c2+c3)) * 0.03125f;
  float pr = ((tid == 0) ? -va*va : va*va) + vb*vb;
  s[tid] = pr; __syncthreads();
  for (int st = 128; st; st >>= 1){ if (tid < st) s[tid] += s[tid+st]; __syncthreads(); }
  float den2 = sqrtf(fmaxf(fabsf(s[0]), 1e-8f));
  if (tid < C) mean[tid] = va / den2;
  if (tid + 256 < C) mean[tid + 256] = vb / den2;
  if (tid < 40) scal[tid] = 0.f;   // var accumulator + flatten square-sums
}

// ---------------- Frechet variance, thread-per-point ------------------------
template<int C>
__global__ __launch_bounds__(256) void bn_var_t_kernel(const float* __restrict__ y,
    const float* __restrict__ mean, float* __restrict__ scal, int P){
  __shared__ float sm[C];
  __shared__ float part[4];
  for (int i = threadIdx.x; i < C; i += 256) sm[i] = mean[i];
  __syncthreads();
  float acc = 0.f;
  int stride = gridDim.x * 256;
  for (int p = blockIdx.x*256 + threadIdx.x; p < P; p += stride){
    const float* yp = y + (size_t)p * C;
    float a[C];
    float d1 = 0.f;
    #pragma unroll
    for (int c = 0; c < C; ++c){
      a[c] = yp[c];
      float pr = a[c]*sm[c];
      d1 += (c == 0) ? -pr : pr;
    }
    float xy = d1;
    float dist = acoshf(fmaxf(-xy, 1.f + 1e-7f));
    float d2 = 0.f;
    #pragma unroll
    for (int c = 0; c < C; ++c){
      a[c] = fmaf(xy, sm[c], a[c]);
      float pr = a[c]*a[c];
      d2 += (c == 0) ? -pr : pr;
    }
    float den = sqrtf(fmaxf(d2, 1e-8f));
    float sc = dist / den;
    float corr = -(a[0]*sc) / (1.f + sm[0]);
    float ns = 0.f;
    #pragma unroll
    for (int c = 0; c < C; ++c){
      float uc = fmaf(corr, sm[c] + ((c == 0) ? 1.f : 0.f), a[c]*sc);
      ns = fmaf(uc, uc, ns);
    }
    acc += sqrtf(ns);
  }
  acc = wredf(acc);
  if ((threadIdx.x & 63) == 0) part[threadIdx.x >> 6] = acc;
  __syncthreads();
  if (threadIdx.x == 0)
    atomicAdd(scal, part[0] + part[1] + part[2] + part[3]);
}

// ---------------- BN apply, thread-per-point --------------------------------
template<int C>
__global__ __launch_bounds__(256) void bn_apply_t_kernel(const float* __restrict__ y,
    const float* __restrict__ mean, const float* __restrict__ beta,
    const float* __restrict__ gamma, const float* __restrict__ scal,
    float* __restrict__ hout, int P){
  __shared__ float sm[C];
  __shared__ float sb[C];
  for (int i = threadIdx.x; i < C; i += 256){ sm[i] = mean[i]; sb[i] = beta[i]; }
  __syncthreads();
  int p = blockIdx.x*256 + threadIdx.x;
  if (p >= P) return;
  const float* yp = y + (size_t)p * C;
  float a[C];
  float d1 = 0.f;
  #pragma unroll
  for (int c = 0; c < C; ++c){
    a[c] = yp[c];
    float pr = a[c]*sm[c];
    d1 += (c == 0) ? -pr : pr;
  }
  float xy = d1;
  float dist = acoshf(fmaxf(-xy, 1.f + 1e-7f));
  float d2 = 0.f;
  #pragma unroll
  for (int c = 0; c < C; ++c){
    a[c] = fmaf(xy, sm[c], a[c]);
    float pr = a[c]*a[c];
    d2 += (c == 0) ? -pr : pr;
  }
  float den = sqrtf(fmaxf(d2, 1e-8f));
  float sc = dist / den;
  float corr = -(a[0]*sc) / (1.f + sm[0]);
  float var = scal[0] / (float)P;
  float g = gamma[0] / (var + 1e-5f);
  #pragma unroll
  for (int c = 0; c < C; ++c)
    a[c] = fmaf(corr, sm[c] + ((c == 0) ? 1.f : 0.f), a[c]*sc) * g;
  float d3 = 0.f;
  #pragma unroll
  for (int c = 0; c < C; ++c){
    float pr = a[c]*sb[c];
    d3 += (c == 0) ? -pr : pr;
  }
  float cb = d3 / (1.f + sb[0]);
  float d4 = 0.f;
  #pragma unroll
  for (int c = 0; c < C; ++c){
    a[c] = fmaf(cb, sb[c] + ((c == 0) ? 1.f : 0.f), a[c]);
    float pr = a[c]*a[c];
    d4 += (c == 0) ? -pr : pr;
  }
  float nu = sqrtf(fmaxf(d4, 1e-8f));
  float ch = coshf(nu), shn = sinhf(nu) / nu;
  float* hp = hout + (size_t)p * C;
  float ssum = 0.f;
  #pragma unroll
  for (int c = 1; c < C; ++c){
    float r = fmaxf(fmaf(ch, sb[c], shn*a[c]), 0.f);
    hp[c] = r;
    ssum = fmaf(r, r, ssum);
  }
  hp[0] = sqrtf(ssum + 1.f);
}

// ---------------- L3 (C=257) wave-per-point fallbacks -----------------------
__global__ void bn_var_kernel(const float* __restrict__ y, const float* __restrict__ mean,
                              float* __restrict__ scal, int P, int C){
  __shared__ float smean[260];
  __shared__ float part[4];
  for (int i = threadIdx.x; i < C; i += blockDim.x) smean[i] = mean[i];
  __syncthreads();
  int wv = threadIdx.x >> 6, lane = threadIdx.x & 63;
  int nwaves = gridDim.x * 4;
  float m0 = smean[0];
  float ms[5];
  #pragma unroll
  for (int j = 0; j < 5; ++j){
    int c = lane + 64*j;
    ms[j] = (c < C) ? smean[c] : 0.f;
  }
  float vsum = 0.f;
  for (int p = blockIdx.x*4 + wv; p < P; p += nwaves){
    const float* yp = y + (size_t)p * C;
    float yv[5], nom[5];
    #pragma unroll
    for (int j = 0; j < 5; ++j){
      int c = lane + 64*j;
      yv[j] = (c < C) ? yp[c] : 0.f;
    }
    float d1 = 0.f;
    #pragma unroll
    for (int j = 0; j < 5; ++j){
      int c = lane + 64*j;
      float prd = yv[j]*ms[j];
      d1 += (c == 0) ? -prd : prd;
    }
    float xy = wredf(d1);
    float dist = acoshf(fmaxf(-xy, 1.f + 1e-7f));
    float d2 = 0.f;
    #pragma unroll
    for (int j = 0; j < 5; ++j){
      int c = lane + 64*j;
      nom[j] = yv[j] + xy*ms[j];
      float prd = nom[j]*nom[j];
      d2 += (c == 0) ? -prd : prd;
    }
    float den = sqrtf(fmaxf(wredf(d2), 1e-8f));
    float sc = dist / den;
    float u0 = __shfl(nom[0], 0, 64) * sc;
    float corr = -u0 / (1.f + m0);
    float nsum = 0.f;
    #pragma unroll
    for (int j = 0; j < 5; ++j){
      int c = lane + 64*j;
      float uc = nom[j]*sc + corr*(ms[j] + ((c == 0) ? 1.f : 0.f));
      nsum += uc*uc;
    }
    nsum = wredf(nsum);
    vsum += sqrtf(nsum);
  }
  if (lane == 0) part[wv] = vsum;
  __syncthreads();
  if (threadIdx.x == 0)
    atomicAdd(scal, part[0] + part[1] + part[2] + part[3]);
}

__global__ void bn_apply_kernel(const float* __restrict__ y, const float* __restrict__ mean,
                                const float* __restrict__ beta, const float* __restrict__ gamma,
                                const float* __restrict__ scal, float* __restrict__ hout,
                                int P, int C){
  __shared__ float smean[260];
  __shared__ float sbeta[260];
  for (int i = threadIdx.x; i < C; i += blockDim.x){ smean[i] = mean[i]; sbeta[i] = beta[i]; }
  __syncthreads();
  int wv = threadIdx.x >> 6, lane = threadIdx.x & 63;
  int p = blockIdx.x*4 + wv;
  if (p >= P) return;
  const float* yp = y + (size_t)p * C;
  float yv[5], ms[5], bs[5], nom[5], uc[5], u2[5];
  #pragma unroll
  for (int j = 0; j < 5; ++j){
    int c = lane + 64*j;
    yv[j] = (c < C) ? yp[c] : 0.f;
    ms[j] = (c < C) ? smean[c] : 0.f;
    bs[j] = (c < C) ? sbeta[c] : 0.f;
  }
  float m0 = smean[0], b0 = sbeta[0];
  float d1 = 0.f;
  #pragma unroll
  for (int j = 0; j < 5; ++j){
    int c = lane + 64*j;
    float prd = yv[j]*ms[j];
    d1 += (c == 0) ? -prd : prd;
  }
  float xy = wredf(d1);
  float dist = acoshf(fmaxf(-xy, 1.f + 1e-7f));
  float d2 = 0.f;
  #pragma unroll
  for (int j = 0; j < 5; ++j){
    nom[j] = yv[j] + xy*ms[j];
    int c = lane + 64*j;
    float prd = nom[j]*nom[j];
    d2 += (c == 0) ? -prd : prd;
  }
  float den = sqrtf(fmaxf(wredf(d2), 1e-8f));
  float sc = dist / den;
  float u0 = __shfl(nom[0], 0, 64) * sc;
  float corr = -u0 / (1.f + m0);
  float var = scal[0] / (float)P;
  float g = gamma[0] / (var + 1e-5f);
  #pragma unroll
  for (int j = 0; j < 5; ++j){
    int c = lane + 64*j;
    uc[j] = (nom[j]*sc + corr*(ms[j] + ((c == 0) ? 1.f : 0.f))) * g;
  }
  float d3 = 0.f;
  #pragma unroll
  for (int j = 0; j < 5; ++j){
    int c = lane + 64*j;
    float prd = uc[j]*bs[j];
    d3 += (c == 0) ? -prd : prd;
  }
  float cb = wredf(d3) / (1.f + b0);
  float d4 = 0.f;
  #pragma unroll
  for (int j = 0; j < 5; ++j){
    int c = lane + 64*j;
    u2[j] = uc[j] + cb*(bs[j] + ((c == 0) ? 1.f : 0.f));
    float prd = u2[j]*u2[j];
    d4 += (c == 0) ? -prd : prd;
  }
  float nu = sqrtf(fmaxf(wredf(d4), 1e-8f));
  float ch = coshf(nu), shn = sinhf(nu) / nu;
  float ssum = 0.f;
  float* hp = hout + (size_t)p * C;
  #pragma unroll
  for (int j = 0; j < 5; ++j){
    int c = lane + 64*j;
    if (c > 0 && c < C){
      float r = ch*sbeta[c] + shn*u2[j];
      r = fmaxf(r, 0.f);
      hp[c] = r;
      ssum += r*r;
    }
  }
  ssum = wredf(ssum);
  if (lane == 0) hp[0] = sqrtf(ssum + 1.f);
}

// ---------------- flatten h4 (B,256,257) -> (B,65537) + square sums ---------
__global__ void flatten_kernel(const float* __restrict__ h, float* __restrict__ flat,
                               float* __restrict__ scal){
  __shared__ float s[256];
  int tid = threadIdx.x;
  int idx = blockIdx.x*256 + tid;
  int b = idx >> 16, r = idx & 65535;
  int n = r >> 8, c = r & 255;
  float v = h[(((size_t)b << 8) + n)*257 + 1 + c];
  flat[(size_t)b*65537 + 1 + r] = v;
  s[tid] = v*v; __syncthreads();
  for (int st = 128; st; st >>= 1){ if (tid < st) s[tid] += s[tid+st]; __syncthreads(); }
  if (tid == 0) atomicAdd(&scal[1 + b], s[0]);
}

__global__ void flat_time_kernel(float* __restrict__ flat, const float* __restrict__ scal){
  int b = threadIdx.x;
  if (b < 32) flat[(size_t)b*65537] = sqrtf(scal[1 + b] + 1.f);
}

// ---------------- head GEMM: split-K, h in LDS, W streamed ------------------
__global__ __launch_bounds__(256) void fgemm_kernel(const float* __restrict__ flat,
    const float* __restrict__ wm, const float* __restrict__ wv,
    float* __restrict__ mvacc){
  __shared__ float hch[256*33];
  int tid = threadIdx.x;
  int k0 = blockIdx.x * 256;
  int obase = blockIdx.y * 32;
  {
    int k = k0 + tid;
    for (int b2 = 0; b2 < 32; ++b2){
      float v = (k < 65537) ? flat[(size_t)b2*65537 + k] : 0.f;
      hch[tid*33 + b2] = v;
    }
  }
  __syncthreads();
  int b = tid & 31, os = tid >> 5;
  const float* rows[4];
  float accv[4] = {0.f, 0.f, 0.f, 0.f};
  #pragma unroll
  for (int r = 0; r < 4; ++r){
    int o = obase + os + r*8;
    rows[r] = (o < 512) ? (wm + (size_t)(o + 1)*65537) : (wv + (size_t)(o - 511)*65537);
  }
  int kRem = min(256, 65537 - k0);
  int k4 = kRem & ~3;
  for (int k = 0; k < k4; k += 4){
    float h0 = hch[(k+0)*33 + b], h1 = hch[(k+1)*33 + b];
    float h2 = hch[(k+2)*33 + b], h3 = hch[(k+3)*33 + b];
    #pragma unroll
    for (int r = 0; r < 4; ++r){
      const float* rw = rows[r] + k0 + k;
      accv[r] += h0*rw[0] + h1*rw[1] + h2*rw[2] + h3*rw[3];
    }
  }
  for (int k = k4; k < kRem; ++k){
    float hv = hch[k*33 + b];
    #pragma unroll
    for (int r = 0; r < 4; ++r) accv[r] += hv * rows[r][k0 + k];
  }
  #pragma unroll
  for (int r = 0; r < 4; ++r){
    int o = obase + os + r*8;
    atomicAdd(&mvacc[o*32 + b], accv[r]);
  }
}

// ---------------- finalize: bias, time, softplus ----------------------------
__global__ void finalize_kernel(const float* __restrict__ mvacc, const float* __restrict__ bm,
                                const float* __restrict__ bv, float* __restrict__ out){
  __shared__ float s[256];
  int b = blockIdx.x, tid = threadIdx.x;
  float m0 = mvacc[tid*32 + b] + bm[tid + 1];
  float m1 = mvacc[(tid + 256)*32 + b] + bm[tid + 257];
  s[tid] = m0*m0 + m1*m1; __syncthreads();
  for (int st = 128; st; st >>= 1){ if (tid < st) s[tid] += s[tid+st]; __syncthreads(); }
  float t = sqrtf(s[0] + 1.f);
  float* om = out + (size_t)b*513;
  om[1 + tid] = m0;
  om[1 + tid + 256] = m1;
  if (tid == 0) om[0] = t;
  float v0 = mvacc[(512 + tid)*32 + b] + bv[tid + 1];
  float v1 = mvacc[(512 + tid + 256)*32 + b] + bv[tid + 257];
  float sp0 = fmaxf(v0, 0.f) + log1pf(expf(-fabsf(v0)));
  float sp1 = fmaxf(v1, 0.f) + log1pf(expf(-fabsf(v1)));
  float* ov = out + 32*513 + (size_t)b*512;
  ov[tid] = fmaxf(sp0, 1e-5f);
  ov[tid + 256] = fmaxf(sp1, 1e-5f);
}

extern "C" void kernel_launch(void* const* d_in, const int* in_sizes, int n_in,
                              void* d_out, int out_size, void* d_ws, size_t ws_size,
                              hipStream_t stream){
  const float* x  = (const float*)d_in[0];
  const float* cw[4] = {(const float*)d_in[1], (const float*)d_in[5], (const float*)d_in[9],  (const float*)d_in[13]};
  const float* cb[4] = {(const float*)d_in[2], (const float*)d_in[6], (const float*)d_in[10], (const float*)d_in[14]};
  const float* bb[4] = {(const float*)d_in[3], (const float*)d_in[7], (const float*)d_in[11], (const float*)d_in[15]};
  const float* bg[4] = {(const float*)d_in[4], (const float*)d_in[8], (const float*)d_in[12], (const float*)d_in[16]};
  const float* wm = (const float*)d_in[17];
  const float* bm = (const float*)d_in[18];
  const float* wv = (const float*)d_in[19];
  const float* bv = (const float*)d_in[20];
  float* ws = (float*)d_ws;

  // workspace layout (floats)
  float* S[3] = { ws, ws + 9000000, ws + 26400000 };      // 9M / 17.4M / 17.4M
  // red2/cent1 live in S1's tail slack: only layer-0 y (17.30M floats) exceeds
  // S1 offset 17.30M; red2 sits at offset 17.302M, cent1 at 17.370M.
  float* red2  = ws + 26302000;                           // <= 68k floats
  float* cent1 = ws + 26370000;                           // <= 32*257 floats
  float* meanp = ws + 43810000;                           // up to 257
  float* scal  = ws + 43811000;                           // [0]=var sum, [1..32]=flat sq
  float* mvacc = ws + 43812000;                           // 1024*32

  hipMemsetAsync(mvacc, 0, 32768*sizeof(float), stream);

  h0_kernel<<<8192, 256, 0, stream>>>(x, S[0]);

  const int HinA[4]  = {256, 128, 64, 32};
  const int SinA[4]  = {3, 32, 64, 128};
  const int HoA[4]   = {128, 64, 32, 16};
  const int CoutA[4] = {33, 65, 129, 257};
  const int KA[4]    = {28, 289, 577, 1153};
  const int BPBA[4]  = {64, 32, 16, 8};

  int cur = 0;
  for (int i = 0; i < 4; ++i){
    int Hin = HinA[i], Win = HinA[i], Cin = SinA[i] + 1;
    int Ho = HoA[i], Wo = HoA[i], Cout = CoutA[i], K = KA[i];
    int BPB = BPBA[i];
    float* hin  = S[cur];
    float* y    = S[(cur + 1) % 3];
    float* hout = S[(cur + 2) % 3];
    int tiles = (Ho/8) * (Wo/8);
    dim3 g(tiles, 32, (Cout - 1 + 63)/64);
    conv_kernel<<<g, 256, 0, stream>>>(hin, cw[i], cb[i], y, Hin, Win, Cin, Ho, Wo, Cout, K);
    int N = Ho * Wo;
    int P = 32 * N;
    int pb = P / 256;                       // P is always a multiple of 256
    switch (i){
      case 0: time_t_kernel<33><<<pb, 256, 0, stream>>>(y, P); break;
      case 1: time_t_kernel<65><<<pb, 256, 0, stream>>>(y, P); break;
      case 2: time_t_kernel<129><<<pb, 256, 0, stream>>>(y, P); break;
      case 3: time_t_kernel<257><<<pb, 256, 0, stream>>>(y, P); break;
    }
    rsum_part_kernel<<<dim3(BPB, 32), 256, 0, stream>>>(y, red2, N, Cout, BPB);
    cent1_kernel<<<32, 256, 0, stream>>>(red2, cent1, N, Cout, BPB);
    stats2_kernel<<<1, 256, 0, stream>>>(cent1, meanp, scal, Cout);
    int vb = min(pb, 2048);
    switch (i){
      case 0:
        bn_var_t_kernel<33><<<vb, 256, 0, stream>>>(y, meanp, scal, P);
        bn_apply_t_kernel<33><<<pb, 256, 0, stream>>>(y, meanp, bb[i], bg[i], scal, hout, P);
        break;
      case 1:
        bn_var_t_kernel<65><<<vb, 256, 0, stream>>>(y, meanp, scal, P);
        bn_apply_t_kernel<65><<<pb, 256, 0, stream>>>(y, meanp, bb[i], bg[i], scal, hout, P);
        break;
      case 2:
        bn_var_t_kernel<129><<<vb, 256, 0, stream>>>(y, meanp, scal, P);
        bn_apply_t_kernel<129><<<pb, 256, 0, stream>>>(y, meanp, bb[i], bg[i], scal, hout, P);
        break;
      case 3:
        bn_var_kernel<<<min((P + 3)/4, 2048), 256, 0, stream>>>(y, meanp, scal, P, Cout);
        bn_apply_kernel<<<(P + 3)/4, 256, 0, stream>>>(y, meanp, bb[i], bg[i], scal, hout, P, Cout);
        break;
    }
    cur = (cur + 2) % 3;
  }

  // h4 now in S[cur] (== S[2]); flatten into S[0]
  float* flatp = S[0];
  flatten_kernel<<<8192, 256, 0, stream>>>(S[cur], flatp, scal);
  flat_time_kernel<<<1, 64, 0, stream>>>(flatp, scal);
  fgemm_kernel<<<dim3(257, 32), 256, 0, stream>>>(flatp, wm, wv, mvacc);
  finalize_kernel<<<32, 256, 0, stream>>>(mvacc, bm, bv, (float*)d_out);
}

// Round 5
// 1633.414 us; speedup vs baseline: 1.7047x; 1.0541x over previous
//
#include <hip/hip_runtime.h>
#include <math.h>

#define DEV __device__ __forceinline__

DEV float wredf(float v){
  v += __shfl_xor(v, 32, 64);
  v += __shfl_xor(v, 16, 64);
  v += __shfl_xor(v, 8, 64);
  v += __shfl_xor(v, 4, 64);
  v += __shfl_xor(v, 2, 64);
  v += __shfl_xor(v, 1, 64);
  return v;
}

// ---------------- h0: (B,3,256,256) -> (B,256,256,4) with time ----------------
__global__ void h0_kernel(const float* __restrict__ x, float* __restrict__ h0){
  int idx = blockIdx.x*256 + threadIdx.x;            // < 32*65536
  int b = idx >> 16, p = idx & 65535;
  const float* xb = x + (size_t)b*3*65536;
  float v0 = xb[p], v1 = xb[65536 + p], v2 = xb[131072 + p];
  float4 o;
  o.x = sqrtf(v0*v0 + v1*v1 + v2*v2 + 1.f);
  o.y = v0; o.z = v1; o.w = v2;
  *(float4*)&h0[(size_t)idx*4] = o;
}

// ---------------- conv GEMM: 64 pixels x 64 out-channels, K chunks of 32 -----
__global__ __launch_bounds__(256) void conv_kernel(
    const float* __restrict__ hin, const float* __restrict__ Wm,
    const float* __restrict__ bias, float* __restrict__ yout,
    int Hin, int Win, int Cin, int Ho, int Wo, int Cout, int K){
  __shared__ __align__(16) float A[32][64];
  __shared__ __align__(16) float Wb[32][64];
  int tid = threadIdx.x;
  int tilesX = Wo >> 3;
  int tile = blockIdx.x;
  int b = blockIdx.y;
  int zbase = blockIdx.z * 64;
  int oy0 = (tile / tilesX) * 8, ox0 = (tile % tilesX) * 8;
  int tx = tid & 15, ty = tid >> 4;
  float acc[4][4] = {};
  int nchunks = (K + 31) / 32;
  for (int ch = 0; ch < nchunks; ++ch){
    int k0 = ch * 32;
    for (int idx = tid; idx < 2048; idx += 256){
      int kk = idx >> 6, m = idx & 63;
      int k = k0 + kk;
      float v = 0.f;
      if (k > 0 && k < K){
        int t = k - 1; int c = t / 9; int kp = t - c*9;
        int py = oy0 + (m >> 3), px = ox0 + (m & 7);
        int iy = py*2 + kp/3 - 1;
        int ix = px*2 + (kp - (kp/3)*3) - 1;
        if ((unsigned)iy < (unsigned)Hin && (unsigned)ix < (unsigned)Win)
          v = hin[(((size_t)b*Hin + iy)*Win + ix)*Cin + 1 + c];
      }
      A[kk][m] = v;
    }
    if (k0 == 0 && tid < 64){
      int m = tid;
      int py = oy0 + (m >> 3), px = ox0 + (m & 7);
      float s = 0.f;
      for (int kp = 0; kp < 9; ++kp){
        int iy = py*2 + kp/3 - 1, ix = px*2 + kp%3 - 1;
        float tv = 1.f;  // zero-padded point clamps to sqrt(K)=1
        if ((unsigned)iy < (unsigned)Hin && (unsigned)ix < (unsigned)Win)
          tv = fmaxf(hin[(((size_t)b*Hin + iy)*Win + ix)*Cin], 1.f);
        s += tv*tv;
      }
      A[0][m] = sqrtf(fmaxf(s - 8.f, 0.f));
    }
    for (int idx = tid; idx < 2048; idx += 256){
      int kk = idx >> 6, n = idx & 63;
      int k = k0 + kk;
      int o = zbase + n + 1;
      Wb[kk][n] = (k < K && o < Cout) ? Wm[(size_t)o*K + k] : 0.f;
    }
    __syncthreads();
    #pragma unroll
    for (int kk = 0; kk < 32; ++kk){
      float4 a4 = *(const float4*)&A[kk][tx*4];
      float4 w4 = *(const float4*)&Wb[kk][ty*4];
      float av[4] = {a4.x, a4.y, a4.z, a4.w};
      float wv[4] = {w4.x, w4.y, w4.z, w4.w};
      #pragma unroll
      for (int i = 0; i < 4; ++i)
        #pragma unroll
        for (int j = 0; j < 4; ++j)
          acc[i][j] = fmaf(av[i], wv[j], acc[i][j]);
    }
    __syncthreads();
  }
  #pragma unroll
  for (int j = 0; j < 4; ++j){
    int o = zbase + ty*4 + j + 1;
    if (o < Cout){
      float bv = bias[o];
      #pragma unroll
      for (int i = 0; i < 4; ++i){
        int m = tx*4 + i;
        int py = oy0 + (m >> 3), px = ox0 + (m & 7);
        yout[(((size_t)b*Ho + py)*Wo + px)*Cout + o] = acc[i][j] + bv;
      }
    }
  }
}

// ---------------- time (thread-per-point): y[p][0] = sqrt(sum space^2 + 1) --
template<int C>
__global__ void time_t_kernel(float* __restrict__ y, int P){
  int p = blockIdx.x*256 + threadIdx.x;
  if (p >= P) return;
  float* yp = y + (size_t)p * C;
  float ss = 0.f;
  #pragma unroll
  for (int c = 1; c < C; ++c){ float v = yp[c]; ss = fmaf(v, v, ss); }
  yp[0] = sqrtf(ss + 1.f);
}

// ---------------- per-(b,blk,c) partial channel sums (no atomics) -----------
__global__ void rsum_part_kernel(const float* __restrict__ y, float* __restrict__ red2,
                                 int N, int C, int BPB){
  int b = blockIdx.y, blk = blockIdx.x;
  int chunk = N / BPB;
  int n0 = blk*chunk, n1 = n0 + chunk;
  int tid = threadIdx.x;
  float a0 = 0.f, a1 = 0.f;
  for (int n = n0; n < n1; ++n){
    const float* yp = y + ((size_t)b*N + n) * C;
    if (tid < C) a0 += yp[tid];
    if (tid + 256 < C) a1 += yp[tid + 256];
  }
  float* rp = red2 + ((size_t)b*BPB + blk) * C;
  if (tid < C) rp[tid] = a0;
  if (tid + 256 < C) rp[tid + 256] = a1;
}

// ---------------- stage 1: per-b centroid (32 blocks, chain-broken loads) ----
__global__ void cent1_kernel(const float* __restrict__ red2, float* __restrict__ cent1,
                             int N, int C, int BPB){
  __shared__ float s[256];
  int b = blockIdx.x, tid = threadIdx.x;
  float a0=0.f,a1=0.f,a2=0.f,a3=0.f, c0=0.f,c1=0.f,c2=0.f,c3=0.f;
  for (int blk = 0; blk < BPB; blk += 4){
    const float* r0 = red2 + ((size_t)b*BPB + blk) * C;
    const float* r1 = r0 + C;
    const float* r2 = r0 + 2*(size_t)C;
    const float* r3 = r0 + 3*(size_t)C;
    if (tid < C){ a0 += r0[tid]; a1 += r1[tid]; a2 += r2[tid]; a3 += r3[tid]; }
    if (tid + 256 < C){
      c0 += r0[tid+256]; c1 += r1[tid+256]; c2 += r2[tid+256]; c3 += r3[tid+256];
    }
  }
  float va = ((a0+a1)+(a2+a3)) / (float)N;
  float vb = ((c0+c1)+(c2+c3)) / (float)N;
  float pr = ((tid == 0) ? -va*va : va*va) + vb*vb;   // Minkowski <avg,avg>
  s[tid] = pr; __syncthreads();
  for (int st = 128; st; st >>= 1){ if (tid < st) s[tid] += s[tid+st]; __syncthreads(); }
  float den = sqrtf(fmaxf(fabsf(s[0]), 1e-8f));
  if (tid < C) cent1[(size_t)b*C + tid] = va / den;
  if (tid + 256 < C) cent1[(size_t)b*C + tid + 256] = vb / den;
}

// ---------------- stage 2: centroid of centroids; zero scratch scalars ------
__global__ void stats2_kernel(const float* __restrict__ cent1, float* __restrict__ mean,
                              float* __restrict__ scal, int C){
  __shared__ float s[256];
  int tid = threadIdx.x;
  float a0=0.f,a1=0.f,a2=0.f,a3=0.f, c0=0.f,c1=0.f,c2=0.f,c3=0.f;
  #pragma unroll
  for (int b = 0; b < 32; b += 4){
    const float* r0 = cent1 + (size_t)b*C;
    const float* r1 = r0 + C;
    const float* r2 = r0 + 2*(size_t)C;
    const float* r3 = r0 + 3*(size_t)C;
    if (tid < C){ a0 += r0[tid]; a1 += r1[tid]; a2 += r2[tid]; a3 += r3[tid]; }
    if (tid + 256 < C){
      c0 += r0[tid+256]; c1 += r1[tid+256]; c2 += r2[tid+256]; c3 += r3[tid+256];
    }
  }
  float va = ((a0+a1)+(a2+a3)) * 0.03125f;
  float vb = ((c0+c1)+(c2+c3)) * 0.03125f;
  float pr = ((tid == 0) ? -va*va : va*va) + vb*vb;
  s[tid] = pr; __syncthreads();
  for (int st = 128; st; st >>= 1){ if (tid < st) s[tid] += s[tid+st]; __syncthreads(); }
  float den2 = sqrtf(fmaxf(fabsf(s[0]), 1e-8f));
  if (tid < C) mean[tid] = va / den2;
  if (tid + 256 < C) mean[tid + 256] = vb / den2;
  if (tid < 40) scal[tid] = 0.f;   // var accumulator + flatten square-sums
}

// ---------------- Frechet variance, thread-per-point ------------------------
template<int C>
__global__ __launch_bounds__(256) void bn_var_t_kernel(const float* __restrict__ y,
    const float* __restrict__ mean, float* __restrict__ scal, int P){
  __shared__ float sm[C];
  __shared__ float part[4];
  for (int i = threadIdx.x; i < C; i += 256) sm[i] = mean[i];
  __syncthreads();
  float acc = 0.f;
  int stride = gridDim.x * 256;
  for (int p = blockIdx.x*256 + threadIdx.x; p < P; p += stride){
    const float* yp = y + (size_t)p * C;
    float a[C];
    float d1 = 0.f;
    #pragma unroll
    for (int c = 0; c < C; ++c){
      a[c] = yp[c];
      float pr = a[c]*sm[c];
      d1 += (c == 0) ? -pr : pr;
    }
    float xy = d1;
    float dist = acoshf(fmaxf(-xy, 1.f + 1e-7f));
    float d2 = 0.f;
    #pragma unroll
    for (int c = 0; c < C; ++c){
      a[c] = fmaf(xy, sm[c], a[c]);
      float pr = a[c]*a[c];
      d2 += (c == 0) ? -pr : pr;
    }
    float den = sqrtf(fmaxf(d2, 1e-8f));
    float sc = dist / den;
    float corr = -(a[0]*sc) / (1.f + sm[0]);
    float ns = 0.f;
    #pragma unroll
    for (int c = 0; c < C; ++c){
      float uc = fmaf(corr, sm[c] + ((c == 0) ? 1.f : 0.f), a[c]*sc);
      ns = fmaf(uc, uc, ns);
    }
    acc += sqrtf(ns);
  }
  acc = wredf(acc);
  if ((threadIdx.x & 63) == 0) part[threadIdx.x >> 6] = acc;
  __syncthreads();
  if (threadIdx.x == 0)
    atomicAdd(scal, part[0] + part[1] + part[2] + part[3]);
}

// ---------------- BN apply, thread-per-point --------------------------------
template<int C>
__global__ __launch_bounds__(256) void bn_apply_t_kernel(const float* __restrict__ y,
    const float* __restrict__ mean, const float* __restrict__ beta,
    const float* __restrict__ gamma, const float* __restrict__ scal,
    float* __restrict__ hout, int P){
  __shared__ float sm[C];
  __shared__ float sb[C];
  for (int i = threadIdx.x; i < C; i += 256){ sm[i] = mean[i]; sb[i] = beta[i]; }
  __syncthreads();
  int p = blockIdx.x*256 + threadIdx.x;
  if (p >= P) return;
  const float* yp = y + (size_t)p * C;
  float a[C];
  float d1 = 0.f;
  #pragma unroll
  for (int c = 0; c < C; ++c){
    a[c] = yp[c];
    float pr = a[c]*sm[c];
    d1 += (c == 0) ? -pr : pr;
  }
  float xy = d1;
  float dist = acoshf(fmaxf(-xy, 1.f + 1e-7f));
  float d2 = 0.f;
  #pragma unroll
  for (int c = 0; c < C; ++c){
    a[c] = fmaf(xy, sm[c], a[c]);
    float pr = a[c]*a[c];
    d2 += (c == 0) ? -pr : pr;
  }
  float den = sqrtf(fmaxf(d2, 1e-8f));
  float sc = dist / den;
  float corr = -(a[0]*sc) / (1.f + sm[0]);
  float var = scal[0] / (float)P;
  float g = gamma[0] / (var + 1e-5f);
  #pragma unroll
  for (int c = 0; c < C; ++c)
    a[c] = fmaf(corr, sm[c] + ((c == 0) ? 1.f : 0.f), a[c]*sc) * g;
  float d3 = 0.f;
  #pragma unroll
  for (int c = 0; c < C; ++c){
    float pr = a[c]*sb[c];
    d3 += (c == 0) ? -pr : pr;
  }
  float cb = d3 / (1.f + sb[0]);
  float d4 = 0.f;
  #pragma unroll
  for (int c = 0; c < C; ++c){
    a[c] = fmaf(cb, sb[c] + ((c == 0) ? 1.f : 0.f), a[c]);
    float pr = a[c]*a[c];
    d4 += (c == 0) ? -pr : pr;
  }
  float nu = sqrtf(fmaxf(d4, 1e-8f));
  float ch = coshf(nu), shn = sinhf(nu) / nu;
  float* hp = hout + (size_t)p * C;
  float ssum = 0.f;
  #pragma unroll
  for (int c = 1; c < C; ++c){
    float r = fmaxf(fmaf(ch, sb[c], shn*a[c]), 0.f);
    hp[c] = r;
    ssum = fmaf(r, r, ssum);
  }
  hp[0] = sqrtf(ssum + 1.f);
}

// ---------------- L3 (C=257) wave-per-point fallbacks -----------------------
__global__ void bn_var_kernel(const float* __restrict__ y, const float* __restrict__ mean,
                              float* __restrict__ scal, int P, int C){
  __shared__ float smean[260];
  __shared__ float part[4];
  for (int i = threadIdx.x; i < C; i += blockDim.x) smean[i] = mean[i];
  __syncthreads();
  int wv = threadIdx.x >> 6, lane = threadIdx.x & 63;
  int nwaves = gridDim.x * 4;
  float m0 = smean[0];
  float ms[5];
  #pragma unroll
  for (int j = 0; j < 5; ++j){
    int c = lane + 64*j;
    ms[j] = (c < C) ? smean[c] : 0.f;
  }
  float vsum = 0.f;
  for (int p = blockIdx.x*4 + wv; p < P; p += nwaves){
    const float* yp = y + (size_t)p * C;
    float yv[5], nom[5];
    #pragma unroll
    for (int j = 0; j < 5; ++j){
      int c = lane + 64*j;
      yv[j] = (c < C) ? yp[c] : 0.f;
    }
    float d1 = 0.f;
    #pragma unroll
    for (int j = 0; j < 5; ++j){
      int c = lane + 64*j;
      float prd = yv[j]*ms[j];
      d1 += (c == 0) ? -prd : prd;
    }
    float xy = wredf(d1);
    float dist = acoshf(fmaxf(-xy, 1.f + 1e-7f));
    float d2 = 0.f;
    #pragma unroll
    for (int j = 0; j < 5; ++j){
      int c = lane + 64*j;
      nom[j] = yv[j] + xy*ms[j];
      float prd = nom[j]*nom[j];
      d2 += (c == 0) ? -prd : prd;
    }
    float den = sqrtf(fmaxf(wredf(d2), 1e-8f));
    float sc = dist / den;
    float u0 = __shfl(nom[0], 0, 64) * sc;
    float corr = -u0 / (1.f + m0);
    float nsum = 0.f;
    #pragma unroll
    for (int j = 0; j < 5; ++j){
      int c = lane + 64*j;
      float uc = nom[j]*sc + corr*(ms[j] + ((c == 0) ? 1.f : 0.f));
      nsum += uc*uc;
    }
    nsum = wredf(nsum);
    vsum += sqrtf(nsum);
  }
  if (lane == 0) part[wv] = vsum;
  __syncthreads();
  if (threadIdx.x == 0)
    atomicAdd(scal, part[0] + part[1] + part[2] + part[3]);
}

__global__ void bn_apply_kernel(const float* __restrict__ y, const float* __restrict__ mean,
                                const float* __restrict__ beta, const float* __restrict__ gamma,
                                const float* __restrict__ scal, float* __restrict__ hout,
                                int P, int C){
  __shared__ float smean[260];
  __shared__ float sbeta[260];
  for (int i = threadIdx.x; i < C; i += blockDim.x){ smean[i] = mean[i]; sbeta[i] = beta[i]; }
  __syncthreads();
  int wv = threadIdx.x >> 6, lane = threadIdx.x & 63;
  int p = blockIdx.x*4 + wv;
  if (p >= P) return;
  const float* yp = y + (size_t)p * C;
  float yv[5], ms[5], bs[5], nom[5], uc[5], u2[5];
  #pragma unroll
  for (int j = 0; j < 5; ++j){
    int c = lane + 64*j;
    yv[j] = (c < C) ? yp[c] : 0.f;
    ms[j] = (c < C) ? smean[c] : 0.f;
    bs[j] = (c < C) ? sbeta[c] : 0.f;
  }
  float m0 = smean[0], b0 = sbeta[0];
  float d1 = 0.f;
  #pragma unroll
  for (int j = 0; j < 5; ++j){
    int c = lane + 64*j;
    float prd = yv[j]*ms[j];
    d1 += (c == 0) ? -prd : prd;
  }
  float xy = wredf(d1);
  float dist = acoshf(fmaxf(-xy, 1.f + 1e-7f));
  float d2 = 0.f;
  #pragma unroll
  for (int j = 0; j < 5; ++j){
    nom[j] = yv[j] + xy*ms[j];
    int c = lane + 64*j;
    float prd = nom[j]*nom[j];
    d2 += (c == 0) ? -prd : prd;
  }
  float den = sqrtf(fmaxf(wredf(d2), 1e-8f));
  float sc = dist / den;
  float u0 = __shfl(nom[0], 0, 64) * sc;
  float corr = -u0 / (1.f + m0);
  float var = scal[0] / (float)P;
  float g = gamma[0] / (var + 1e-5f);
  #pragma unroll
  for (int j = 0; j < 5; ++j){
    int c = lane + 64*j;
    uc[j] = (nom[j]*sc + corr*(ms[j] + ((c == 0) ? 1.f : 0.f))) * g;
  }
  float d3 = 0.f;
  #pragma unroll
  for (int j = 0; j < 5; ++j){
    int c = lane + 64*j;
    float prd = uc[j]*bs[j];
    d3 += (c == 0) ? -prd : prd;
  }
  float cb = wredf(d3) / (1.f + b0);
  float d4 = 0.f;
  #pragma unroll
  for (int j = 0; j < 5; ++j){
    int c = lane + 64*j;
    u2[j] = uc[j] + cb*(bs[j] + ((c == 0) ? 1.f : 0.f));
    float prd = u2[j]*u2[j];
    d4 += (c == 0) ? -prd : prd;
  }
  float nu = sqrtf(fmaxf(wredf(d4), 1e-8f));
  float ch = coshf(nu), shn = sinhf(nu) / nu;
  float ssum = 0.f;
  float* hp = hout + (size_t)p * C;
  #pragma unroll
  for (int j = 0; j < 5; ++j){
    int c = lane + 64*j;
    if (c > 0 && c < C){
      float r = ch*sbeta[c] + shn*u2[j];
      r = fmaxf(r, 0.f);
      hp[c] = r;
      ssum += r*r;
    }
  }
  ssum = wredf(ssum);
  if (lane == 0) hp[0] = sqrtf(ssum + 1.f);
}

// ---------------- flatten h4 (B,256,257) -> (B,65537) + square sums ---------
__global__ void flatten_kernel(const float* __restrict__ h, float* __restrict__ flat,
                               float* __restrict__ scal){
  __shared__ float s[256];
  int tid = threadIdx.x;
  int idx = blockIdx.x*256 + tid;
  int b = idx >> 16, r = idx & 65535;
  int n = r >> 8, c = r & 255;
  float v = h[(((size_t)b << 8) + n)*257 + 1 + c];
  flat[(size_t)b*65537 + 1 + r] = v;
  s[tid] = v*v; __syncthreads();
  for (int st = 128; st; st >>= 1){ if (tid < st) s[tid] += s[tid+st]; __syncthreads(); }
  if (tid == 0) atomicAdd(&scal[1 + b], s[0]);
}

__global__ void flat_time_kernel(float* __restrict__ flat, const float* __restrict__ scal){
  int b = threadIdx.x;
  if (b < 32) flat[(size_t)b*65537] = sqrtf(scal[1 + b] + 1.f);
}

// ---------------- head GEMM v2: k across lanes, coalesced W stream ----------
// grid (16 k-chunks, 64 row-blocks); block = 4 waves; wave = 4 rows x 32 b.
// Lane l covers k = 4l..4l+3 of each 256-k subchunk (h via LDS float4,
// W via 4 guarded-aligned scalar loads since rows are odd-offset).
// Cross-lane reduce ONCE at the end; k=65536 column folded into finalize.
__global__ __launch_bounds__(256) void fgemm_kernel(const float* __restrict__ flat,
    const float* __restrict__ wm, const float* __restrict__ wv,
    float* __restrict__ mvacc){
  __shared__ float hlds[32*256];
  int tid = threadIdx.x;
  int wave = tid >> 6, l = tid & 63;
  int k0 = blockIdx.x * 4096;
  int obase = blockIdx.y * 16 + wave * 4;
  const float* rows[4];
  #pragma unroll
  for (int r = 0; r < 4; ++r){
    int o = obase + r;
    rows[r] = (o < 512) ? (wm + (size_t)(o + 1)*65537) : (wv + (size_t)(o - 511)*65537);
  }
  float acc[4][32] = {};
  for (int s = 0; s < 16; ++s){
    int kbase = k0 + s*256;
    #pragma unroll
    for (int b = 0; b < 32; ++b)
      hlds[b*256 + tid] = flat[(size_t)b*65537 + kbase + tid];
    __syncthreads();
    int kl = kbase + 4*l;
    float w0[4], w1[4], w2[4], w3[4];
    #pragma unroll
    for (int r = 0; r < 4; ++r){
      const float* wp = rows[r] + kl;
      w0[r] = wp[0]; w1[r] = wp[1]; w2[r] = wp[2]; w3[r] = wp[3];
    }
    #pragma unroll
    for (int b = 0; b < 32; ++b){
      float4 h4 = *(const float4*)&hlds[b*256 + 4*l];
      #pragma unroll
      for (int r = 0; r < 4; ++r){
        float t0 = fmaf(w0[r], h4.x, acc[r][b]);
        float t1 = fmaf(w1[r], h4.y, t0);
        float t2 = fmaf(w2[r], h4.z, t1);
        acc[r][b] = fmaf(w3[r], h4.w, t2);
      }
    }
    __syncthreads();
  }
  #pragma unroll
  for (int r = 0; r < 4; ++r){
    #pragma unroll
    for (int b = 0; b < 32; ++b){
      float v = wredf(acc[r][b]);
      if (l == 0) atomicAdd(&mvacc[(obase + r)*32 + b], v);
    }
  }
}

// ---------------- finalize: bias, k=65536 tail term, time, softplus ---------
__global__ void finalize_kernel(const float* __restrict__ mvacc, const float* __restrict__ bm,
                                const float* __restrict__ bv,
                                const float* __restrict__ wm, const float* __restrict__ wv,
                                const float* __restrict__ flat, float* __restrict__ out){
  __shared__ float s[256];
  int b = blockIdx.x, tid = threadIdx.x;
  float hl = flat[(size_t)b*65537 + 65536];
  float m0 = mvacc[tid*32 + b] + bm[tid + 1]
           + wm[(size_t)(tid + 1)*65537 + 65536] * hl;
  float m1 = mvacc[(tid + 256)*32 + b] + bm[tid + 257]
           + wm[(size_t)(tid + 257)*65537 + 65536] * hl;
  s[tid] = m0*m0 + m1*m1; __syncthreads();
  for (int st = 128; st; st >>= 1){ if (tid < st) s[tid] += s[tid+st]; __syncthreads(); }
  float t = sqrtf(s[0] + 1.f);
  float* om = out + (size_t)b*513;
  om[1 + tid] = m0;
  om[1 + tid + 256] = m1;
  if (tid == 0) om[0] = t;
  float v0 = mvacc[(512 + tid)*32 + b] + bv[tid + 1]
           + wv[(size_t)(tid + 1)*65537 + 65536] * hl;
  float v1 = mvacc[(512 + tid + 256)*32 + b] + bv[tid + 257]
           + wv[(size_t)(tid + 257)*65537 + 65536] * hl;
  float sp0 = fmaxf(v0, 0.f) + log1pf(expf(-fabsf(v0)));
  float sp1 = fmaxf(v1, 0.f) + log1pf(expf(-fabsf(v1)));
  float* ov = out + 32*513 + (size_t)b*512;
  ov[tid] = fmaxf(sp0, 1e-5f);
  ov[tid + 256] = fmaxf(sp1, 1e-5f);
}

extern "C" void kernel_launch(void* const* d_in, const int* in_sizes, int n_in,
                              void* d_out, int out_size, void* d_ws, size_t ws_size,
                              hipStream_t stream){
  const float* x  = (const float*)d_in[0];
  const float* cw[4] = {(const float*)d_in[1], (const float*)d_in[5], (const float*)d_in[9],  (const float*)d_in[13]};
  const float* cb[4] = {(const float*)d_in[2], (const float*)d_in[6], (const float*)d_in[10], (const float*)d_in[14]};
  const float* bb[4] = {(const float*)d_in[3], (const float*)d_in[7], (const float*)d_in[11], (const float*)d_in[15]};
  const float* bg[4] = {(const float*)d_in[4], (const float*)d_in[8], (const float*)d_in[12], (const float*)d_in[16]};
  const float* wm = (const float*)d_in[17];
  const float* bm = (const float*)d_in[18];
  const float* wv = (const float*)d_in[19];
  const float* bv = (const float*)d_in[20];
  float* ws = (float*)d_ws;

  // workspace layout (floats)
  float* S[3] = { ws, ws + 9000000, ws + 26400000 };      // 9M / 17.4M / 17.4M
  // red2/cent1 live in S1's tail slack: only layer-0 y (17.30M floats) exceeds
  // S1 offset 17.30M; red2 sits at offset 17.302M, cent1 at 17.370M.
  float* red2  = ws + 26302000;                           // <= 68k floats
  float* cent1 = ws + 26370000;                           // <= 32*257 floats
  float* meanp = ws + 43810000;                           // up to 257
  float* scal  = ws + 43811000;                           // [0]=var sum, [1..32]=flat sq
  float* mvacc = ws + 43812000;                           // 1024*32

  hipMemsetAsync(mvacc, 0, 32768*sizeof(float), stream);

  h0_kernel<<<8192, 256, 0, stream>>>(x, S[0]);

  const int HinA[4]  = {256, 128, 64, 32};
  const int SinA[4]  = {3, 32, 64, 128};
  const int HoA[4]   = {128, 64, 32, 16};
  const int CoutA[4] = {33, 65, 129, 257};
  const int KA[4]    = {28, 289, 577, 1153};
  const int BPBA[4]  = {64, 32, 16, 8};

  int cur = 0;
  for (int i = 0; i < 4; ++i){
    int Hin = HinA[i], Win = HinA[i], Cin = SinA[i] + 1;
    int Ho = HoA[i], Wo = HoA[i], Cout = CoutA[i], K = KA[i];
    int BPB = BPBA[i];
    float* hin  = S[cur];
    float* y    = S[(cur + 1) % 3];
    float* hout = S[(cur + 2) % 3];
    int tiles = (Ho/8) * (Wo/8);
    dim3 g(tiles, 32, (Cout - 1 + 63)/64);
    conv_kernel<<<g, 256, 0, stream>>>(hin, cw[i], cb[i], y, Hin, Win, Cin, Ho, Wo, Cout, K);
    int N = Ho * Wo;
    int P = 32 * N;
    int pb = P / 256;                       // P is always a multiple of 256
    switch (i){
      case 0: time_t_kernel<33><<<pb, 256, 0, stream>>>(y, P); break;
      case 1: time_t_kernel<65><<<pb, 256, 0, stream>>>(y, P); break;
      case 2: time_t_kernel<129><<<pb, 256, 0, stream>>>(y, P); break;
      case 3: time_t_kernel<257><<<pb, 256, 0, stream>>>(y, P); break;
    }
    rsum_part_kernel<<<dim3(BPB, 32), 256, 0, stream>>>(y, red2, N, Cout, BPB);
    cent1_kernel<<<32, 256, 0, stream>>>(red2, cent1, N, Cout, BPB);
    stats2_kernel<<<1, 256, 0, stream>>>(cent1, meanp, scal, Cout);
    int vb = min(pb, 2048);
    switch (i){
      case 0:
        bn_var_t_kernel<33><<<vb, 256, 0, stream>>>(y, meanp, scal, P);
        bn_apply_t_kernel<33><<<pb, 256, 0, stream>>>(y, meanp, bb[i], bg[i], scal, hout, P);
        break;
      case 1:
        bn_var_t_kernel<65><<<vb, 256, 0, stream>>>(y, meanp, scal, P);
        bn_apply_t_kernel<65><<<pb, 256, 0, stream>>>(y, meanp, bb[i], bg[i], scal, hout, P);
        break;
      case 2:
        bn_var_t_kernel<129><<<vb, 256, 0, stream>>>(y, meanp, scal, P);
        bn_apply_t_kernel<129><<<pb, 256, 0, stream>>>(y, meanp, bb[i], bg[i], scal, hout, P);
        break;
      case 3:
        bn_var_kernel<<<min((P + 3)/4, 2048), 256, 0, stream>>>(y, meanp, scal, P, Cout);
        bn_apply_kernel<<<(P + 3)/4, 256, 0, stream>>>(y, meanp, bb[i], bg[i], scal, hout, P, Cout);
        break;
    }
    cur = (cur + 2) % 3;
  }

  // h4 now in S[cur] (== S[2]); flatten into S[0]
  float* flatp = S[0];
  flatten_kernel<<<8192, 256, 0, stream>>>(S[cur], flatp, scal);
  flat_time_kernel<<<1, 64, 0, stream>>>(flatp, scal);
  fgemm_kernel<<<dim3(16, 64), 256, 0, stream>>>(flatp, wm, wv, mvacc);
  finalize_kernel<<<32, 256, 0, stream>>>(mvacc, bm, bv, wm, wv, flatp, (float*)d_out);
}

// Round 6
// 1254.595 us; speedup vs baseline: 2.2194x; 1.3019x over previous
//
#include <hip/hip_runtime.h>
#include <math.h>

#define DEV __device__ __forceinline__

typedef float f32x4 __attribute__((ext_vector_type(4)));
typedef __bf16 bf16x8 __attribute__((ext_vector_type(8)));

DEV unsigned short f2bf(float f){
  unsigned int u = __float_as_uint(f);
  u = (u + 0x7FFFu + ((u >> 16) & 1u)) >> 16;   // RNE
  return (unsigned short)u;
}
DEV float bf2f(unsigned short s){
  return __uint_as_float(((unsigned int)s) << 16);
}

DEV float wredf(float v){
  v += __shfl_xor(v, 32, 64);
  v += __shfl_xor(v, 16, 64);
  v += __shfl_xor(v, 8, 64);
  v += __shfl_xor(v, 4, 64);
  v += __shfl_xor(v, 2, 64);
  v += __shfl_xor(v, 1, 64);
  return v;
}

// ---------------- h0: (B,3,256,256) -> (B,256,256,4) bf16 with time ---------
__global__ void h0_kernel(const float* __restrict__ x, unsigned short* __restrict__ h0){
  int idx = blockIdx.x*256 + threadIdx.x;            // < 32*65536
  int b = idx >> 16, p = idx & 65535;
  const float* xb = x + (size_t)b*3*65536;
  float v0 = xb[p], v1 = xb[65536 + p], v2 = xb[131072 + p];
  float t = sqrtf(v0*v0 + v1*v1 + v2*v2 + 1.f);
  ushort4 o;
  o.x = f2bf(t); o.y = f2bf(v0); o.z = f2bf(v1); o.w = f2bf(v2);
  *(ushort4*)&h0[(size_t)idx*4] = o;
}

// ---------------- MFMA conv: 64-pixel x NT-outch tile, bf16, fp32 accum -----
// A (im2col, bf16) and B^T (weights, bf16) staged in LDS [.. ][56] (112B rows:
// 16B-aligned for ds_read_b128, 8-bank spread -> 2-way = free).
// mfma_f32_16x16x32_bf16 layout: A row=lane&15,k=(lane>>4)*8+e; B^T same form;
// D col=lane&15, row=(lane>>4)*4+r  [m89-verified].
template<int CIN, int COUT, int K, int NT>
__global__ __launch_bounds__(256) void conv_mfma_kernel(
    const unsigned short* __restrict__ hin, const float* __restrict__ Wm,
    const float* __restrict__ bias, float* __restrict__ y,
    int Hin, int Ho){
  constexpr int KC = (K + 31) / 32;
  constexpr int WN = (NT == 64) ? 2 : 1;     // waves along N
  constexpr int MI = (NT == 64) ? 2 : 1;     // 16-row frags per wave
  constexpr int NI = 2;                      // 16-col frags per wave
  __shared__ __align__(16) unsigned short A_lds[64][56];
  __shared__ __align__(16) unsigned short B_lds[NT][56];
  int tid = threadIdx.x;
  int wave = tid >> 6, lane = tid & 63;
  int tilesX = Ho >> 3;
  int tile = blockIdx.x;
  int b = blockIdx.y;
  int zbase = blockIdx.z * NT;
  int oy0 = (tile / tilesX) * 8, ox0 = (tile % tilesX) * 8;
  int m0 = (wave / WN) * (MI * 16);
  int n0 = (wave % WN) * (NI * 16);
  int row = lane & 15, kb = lane >> 4;
  f32x4 zero = {0.f, 0.f, 0.f, 0.f};
  f32x4 acc[MI][NI];
  #pragma unroll
  for (int mi = 0; mi < MI; ++mi)
    #pragma unroll
    for (int ni = 0; ni < NI; ++ni) acc[mi][ni] = zero;

  for (int ch = 0; ch < KC; ++ch){
    int k0 = ch * 32;
    // stage A (im2col gather, already bf16 bits)
    for (int i = tid; i < 64*32; i += 256){
      int m = i >> 5, kk = i & 31;
      int k = k0 + kk;
      if (k == 0) continue;                  // t-row written below
      unsigned short v = 0;
      if (k < K){
        int t = k - 1; int c = t / 9; int kp = t - c*9;
        int py = oy0 + (m >> 3), px = ox0 + (m & 7);
        int iy = py*2 + kp/3 - 1;
        int ix = px*2 + (kp - (kp/3)*3) - 1;
        if ((unsigned)iy < (unsigned)Hin && (unsigned)ix < (unsigned)Hin)
          v = hin[(((size_t)b*Hin + iy)*Hin + ix)*CIN + 1 + c];
      }
      A_lds[m][kk] = v;
    }
    if (ch == 0 && tid < 64){                // Lorentz concat time row (k=0)
      int m = tid;
      int py = oy0 + (m >> 3), px = ox0 + (m & 7);
      float s = 0.f;
      for (int kp = 0; kp < 9; ++kp){
        int iy = py*2 + kp/3 - 1, ix = px*2 + kp%3 - 1;
        float tv = 1.f;                      // zero-padded point -> sqrt(K)=1
        if ((unsigned)iy < (unsigned)Hin && (unsigned)ix < (unsigned)Hin)
          tv = fmaxf(bf2f(hin[(((size_t)b*Hin + iy)*Hin + ix)*CIN]), 1.f);
        s = fmaf(tv, tv, s);
      }
      A_lds[m][0] = f2bf(sqrtf(fmaxf(s - 8.f, 0.f)));
    }
    // stage B^T (W rows zbase+1 .. zbase+NT, converted to bf16)
    for (int i = tid; i < NT*32; i += 256){
      int n = i >> 5, kk = i & 31;
      int k = k0 + kk;
      B_lds[n][kk] = (k < K) ? f2bf(Wm[(size_t)(zbase + 1 + n)*K + k]) : (unsigned short)0;
    }
    __syncthreads();
    bf16x8 af[MI], bfr[NI];
    #pragma unroll
    for (int mi = 0; mi < MI; ++mi)
      af[mi] = *(const bf16x8*)&A_lds[m0 + 16*mi + row][kb*8];
    #pragma unroll
    for (int ni = 0; ni < NI; ++ni)
      bfr[ni] = *(const bf16x8*)&B_lds[n0 + 16*ni + row][kb*8];
    #pragma unroll
    for (int mi = 0; mi < MI; ++mi)
      #pragma unroll
      for (int ni = 0; ni < NI; ++ni)
        acc[mi][ni] = __builtin_amdgcn_mfma_f32_16x16x32_bf16(af[mi], bfr[ni], acc[mi][ni], 0, 0, 0);
    __syncthreads();
  }
  // epilogue: bias + scatter to (B,Ho,Wo,COUT), channels 1..COUT-1
  #pragma unroll
  for (int mi = 0; mi < MI; ++mi)
    #pragma unroll
    for (int ni = 0; ni < NI; ++ni){
      int col = n0 + 16*ni + row;
      int o = zbase + 1 + col;
      float bv = bias[o];
      #pragma unroll
      for (int r = 0; r < 4; ++r){
        int m = m0 + 16*mi + kb*4 + r;
        int py = oy0 + (m >> 3), px = ox0 + (m & 7);
        y[(((size_t)b*Ho + py)*Ho + px)*COUT + o] = acc[mi][ni][r] + bv;
      }
    }
}

// ---------------- time (thread-per-point): y[p][0] = sqrt(sum space^2 + 1) --
template<int C>
__global__ void time_t_kernel(float* __restrict__ y, int P){
  int p = blockIdx.x*256 + threadIdx.x;
  if (p >= P) return;
  float* yp = y + (size_t)p * C;
  float ss = 0.f;
  #pragma unroll
  for (int c = 1; c < C; ++c){ float v = yp[c]; ss = fmaf(v, v, ss); }
  yp[0] = sqrtf(ss + 1.f);
}

// ---------------- per-(b,blk,c) partial channel sums (no atomics) -----------
__global__ void rsum_part_kernel(const float* __restrict__ y, float* __restrict__ red2,
                                 int N, int C, int BPB){
  int b = blockIdx.y, blk = blockIdx.x;
  int chunk = N / BPB;
  int n0 = blk*chunk, n1 = n0 + chunk;
  int tid = threadIdx.x;
  float a0 = 0.f, a1 = 0.f;
  for (int n = n0; n < n1; ++n){
    const float* yp = y + ((size_t)b*N + n) * C;
    if (tid < C) a0 += yp[tid];
    if (tid + 256 < C) a1 += yp[tid + 256];
  }
  float* rp = red2 + ((size_t)b*BPB + blk) * C;
  if (tid < C) rp[tid] = a0;
  if (tid + 256 < C) rp[tid + 256] = a1;
}

// ---------------- stage 1: per-b centroid (32 blocks, chain-broken loads) ----
__global__ void cent1_kernel(const float* __restrict__ red2, float* __restrict__ cent1,
                             int N, int C, int BPB){
  __shared__ float s[256];
  int b = blockIdx.x, tid = threadIdx.x;
  float a0=0.f,a1=0.f,a2=0.f,a3=0.f, c0=0.f,c1=0.f,c2=0.f,c3=0.f;
  for (int blk = 0; blk < BPB; blk += 4){
    const float* r0 = red2 + ((size_t)b*BPB + blk) * C;
    const float* r1 = r0 + C;
    const float* r2 = r0 + 2*(size_t)C;
    const float* r3 = r0 + 3*(size_t)C;
    if (tid < C){ a0 += r0[tid]; a1 += r1[tid]; a2 += r2[tid]; a3 += r3[tid]; }
    if (tid + 256 < C){
      c0 += r0[tid+256]; c1 += r1[tid+256]; c2 += r2[tid+256]; c3 += r3[tid+256];
    }
  }
  float va = ((a0+a1)+(a2+a3)) / (float)N;
  float vb = ((c0+c1)+(c2+c3)) / (float)N;
  float pr = ((tid == 0) ? -va*va : va*va) + vb*vb;   // Minkowski <avg,avg>
  s[tid] = pr; __syncthreads();
  for (int st = 128; st; st >>= 1){ if (tid < st) s[tid] += s[tid+st]; __syncthreads(); }
  float den = sqrtf(fmaxf(fabsf(s[0]), 1e-8f));
  if (tid < C) cent1[(size_t)b*C + tid] = va / den;
  if (tid + 256 < C) cent1[(size_t)b*C + tid + 256] = vb / den;
}

// ---------------- stage 2: centroid of centroids; zero scratch scalars ------
__global__ void stats2_kernel(const float* __restrict__ cent1, float* __restrict__ mean,
                              float* __restrict__ scal, int C){
  __shared__ float s[256];
  int tid = threadIdx.x;
  float a0=0.f,a1=0.f,a2=0.f,a3=0.f, c0=0.f,c1=0.f,c2=0.f,c3=0.f;
  #pragma unroll
  for (int b = 0; b < 32; b += 4){
    const float* r0 = cent1 + (size_t)b*C;
    const float* r1 = r0 + C;
    const float* r2 = r0 + 2*(size_t)C;
    const float* r3 = r0 + 3*(size_t)C;
    if (tid < C){ a0 += r0[tid]; a1 += r1[tid]; a2 += r2[tid]; a3 += r3[tid]; }
    if (tid + 256 < C){
      c0 += r0[tid+256]; c1 += r1[tid+256]; c2 += r2[tid+256]; c3 += r3[tid+256];
    }
  }
  float va = ((a0+a1)+(a2+a3)) * 0.03125f;
  float vb = ((c0+c1)+(c2+c3)) * 0.03125f;
  float pr = ((tid == 0) ? -va*va : va*va) + vb*vb;
  s[tid] = pr; __syncthreads();
  for (int st = 128; st; st >>= 1){ if (tid < st) s[tid] += s[tid+st]; __syncthreads(); }
  float den2 = sqrtf(fmaxf(fabsf(s[0]), 1e-8f));
  if (tid < C) mean[tid] = va / den2;
  if (tid + 256 < C) mean[tid + 256] = vb / den2;
  if (tid < 40) scal[tid] = 0.f;   // var accumulator + flatten square-sums
}

// ---------------- Frechet variance, thread-per-point ------------------------
template<int C>
__global__ __launch_bounds__(256) void bn_var_t_kernel(const float* __restrict__ y,
    const float* __restrict__ mean, float* __restrict__ scal, int P){
  __shared__ float sm[C];
  __shared__ float part[4];
  for (int i = threadIdx.x; i < C; i += 256) sm[i] = mean[i];
  __syncthreads();
  float acc = 0.f;
  int stride = gridDim.x * 256;
  for (int p = blockIdx.x*256 + threadIdx.x; p < P; p += stride){
    const float* yp = y + (size_t)p * C;
    float a[C];
    float d1 = 0.f;
    #pragma unroll
    for (int c = 0; c < C; ++c){
      a[c] = yp[c];
      float pr = a[c]*sm[c];
      d1 += (c == 0) ? -pr : pr;
    }
    float xy = d1;
    float dist = acoshf(fmaxf(-xy, 1.f + 1e-7f));
    float d2 = 0.f;
    #pragma unroll
    for (int c = 0; c < C; ++c){
      a[c] = fmaf(xy, sm[c], a[c]);
      float pr = a[c]*a[c];
      d2 += (c == 0) ? -pr : pr;
    }
    float den = sqrtf(fmaxf(d2, 1e-8f));
    float sc = dist / den;
    float corr = -(a[0]*sc) / (1.f + sm[0]);
    float ns = 0.f;
    #pragma unroll
    for (int c = 0; c < C; ++c){
      float uc = fmaf(corr, sm[c] + ((c == 0) ? 1.f : 0.f), a[c]*sc);
      ns = fmaf(uc, uc, ns);
    }
    acc += sqrtf(ns);
  }
  acc = wredf(acc);
  if ((threadIdx.x & 63) == 0) part[threadIdx.x >> 6] = acc;
  __syncthreads();
  if (threadIdx.x == 0)
    atomicAdd(scal, part[0] + part[1] + part[2] + part[3]);
}

// ---------------- BN apply, thread-per-point, bf16 output (layers 0-2) ------
template<int C>
__global__ __launch_bounds__(256) void bn_apply_bf_kernel(const float* __restrict__ y,
    const float* __restrict__ mean, const float* __restrict__ beta,
    const float* __restrict__ gamma, const float* __restrict__ scal,
    unsigned short* __restrict__ hout, int P){
  __shared__ float sm[C];
  __shared__ float sb[C];
  for (int i = threadIdx.x; i < C; i += 256){ sm[i] = mean[i]; sb[i] = beta[i]; }
  __syncthreads();
  int p = blockIdx.x*256 + threadIdx.x;
  if (p >= P) return;
  const float* yp = y + (size_t)p * C;
  float a[C];
  float d1 = 0.f;
  #pragma unroll
  for (int c = 0; c < C; ++c){
    a[c] = yp[c];
    float pr = a[c]*sm[c];
    d1 += (c == 0) ? -pr : pr;
  }
  float xy = d1;
  float dist = acoshf(fmaxf(-xy, 1.f + 1e-7f));
  float d2 = 0.f;
  #pragma unroll
  for (int c = 0; c < C; ++c){
    a[c] = fmaf(xy, sm[c], a[c]);
    float pr = a[c]*a[c];
    d2 += (c == 0) ? -pr : pr;
  }
  float den = sqrtf(fmaxf(d2, 1e-8f));
  float sc = dist / den;
  float corr = -(a[0]*sc) / (1.f + sm[0]);
  float var = scal[0] / (float)P;
  float g = gamma[0] / (var + 1e-5f);
  #pragma unroll
  for (int c = 0; c < C; ++c)
    a[c] = fmaf(corr, sm[c] + ((c == 0) ? 1.f : 0.f), a[c]*sc) * g;
  float d3 = 0.f;
  #pragma unroll
  for (int c = 0; c < C; ++c){
    float pr = a[c]*sb[c];
    d3 += (c == 0) ? -pr : pr;
  }
  float cb = d3 / (1.f + sb[0]);
  float d4 = 0.f;
  #pragma unroll
  for (int c = 0; c < C; ++c){
    a[c] = fmaf(cb, sb[c] + ((c == 0) ? 1.f : 0.f), a[c]);
    float pr = a[c]*a[c];
    d4 += (c == 0) ? -pr : pr;
  }
  float nu = sqrtf(fmaxf(d4, 1e-8f));
  float ch = coshf(nu), shn = sinhf(nu) / nu;
  unsigned short* hp = hout + (size_t)p * C;
  float ssum = 0.f;
  #pragma unroll
  for (int c = 1; c < C; ++c){
    float r = fmaxf(fmaf(ch, sb[c], shn*a[c]), 0.f);
    hp[c] = f2bf(r);
    ssum = fmaf(r, r, ssum);
  }
  hp[0] = f2bf(sqrtf(ssum + 1.f));
}

// ---------------- L3 (C=257) wave-per-point fallbacks (fp32 out) ------------
__global__ void bn_var_kernel(const float* __restrict__ y, const float* __restrict__ mean,
                              float* __restrict__ scal, int P, int C){
  __shared__ float smean[260];
  __shared__ float part[4];
  for (int i = threadIdx.x; i < C; i += blockDim.x) smean[i] = mean[i];
  __syncthreads();
  int wv = threadIdx.x >> 6, lane = threadIdx.x & 63;
  int nwaves = gridDim.x * 4;
  float m0 = smean[0];
  float ms[5];
  #pragma unroll
  for (int j = 0; j < 5; ++j){
    int c = lane + 64*j;
    ms[j] = (c < C) ? smean[c] : 0.f;
  }
  float vsum = 0.f;
  for (int p = blockIdx.x*4 + wv; p < P; p += nwaves){
    const float* yp = y + (size_t)p * C;
    float yv[5], nom[5];
    #pragma unroll
    for (int j = 0; j < 5; ++j){
      int c = lane + 64*j;
      yv[j] = (c < C) ? yp[c] : 0.f;
    }
    float d1 = 0.f;
    #pragma unroll
    for (int j = 0; j < 5; ++j){
      int c = lane + 64*j;
      float prd = yv[j]*ms[j];
      d1 += (c == 0) ? -prd : prd;
    }
    float xy = wredf(d1);
    float dist = acoshf(fmaxf(-xy, 1.f + 1e-7f));
    float d2 = 0.f;
    #pragma unroll
    for (int j = 0; j < 5; ++j){
      int c = lane + 64*j;
      nom[j] = yv[j] + xy*ms[j];
      float prd = nom[j]*nom[j];
      d2 += (c == 0) ? -prd : prd;
    }
    float den = sqrtf(fmaxf(wredf(d2), 1e-8f));
    float sc = dist / den;
    float u0 = __shfl(nom[0], 0, 64) * sc;
    float corr = -u0 / (1.f + m0);
    float nsum = 0.f;
    #pragma unroll
    for (int j = 0; j < 5; ++j){
      int c = lane + 64*j;
      float uc = nom[j]*sc + corr*(ms[j] + ((c == 0) ? 1.f : 0.f));
      nsum += uc*uc;
    }
    nsum = wredf(nsum);
    vsum += sqrtf(nsum);
  }
  if (lane == 0) part[wv] = vsum;
  __syncthreads();
  if (threadIdx.x == 0)
    atomicAdd(scal, part[0] + part[1] + part[2] + part[3]);
}

__global__ void bn_apply_kernel(const float* __restrict__ y, const float* __restrict__ mean,
                                const float* __restrict__ beta, const float* __restrict__ gamma,
                                const float* __restrict__ scal, float* __restrict__ hout,
                                int P, int C){
  __shared__ float smean[260];
  __shared__ float sbeta[260];
  for (int i = threadIdx.x; i < C; i += blockDim.x){ smean[i] = mean[i]; sbeta[i] = beta[i]; }
  __syncthreads();
  int wv = threadIdx.x >> 6, lane = threadIdx.x & 63;
  int p = blockIdx.x*4 + wv;
  if (p >= P) return;
  const float* yp = y + (size_t)p * C;
  float yv[5], ms[5], bs[5], nom[5], uc[5], u2[5];
  #pragma unroll
  for (int j = 0; j < 5; ++j){
    int c = lane + 64*j;
    yv[j] = (c < C) ? yp[c] : 0.f;
    ms[j] = (c < C) ? smean[c] : 0.f;
    bs[j] = (c < C) ? sbeta[c] : 0.f;
  }
  float m0 = smean[0], b0 = sbeta[0];
  float d1 = 0.f;
  #pragma unroll
  for (int j = 0; j < 5; ++j){
    int c = lane + 64*j;
    float prd = yv[j]*ms[j];
    d1 += (c == 0) ? -prd : prd;
  }
  float xy = wredf(d1);
  float dist = acoshf(fmaxf(-xy, 1.f + 1e-7f));
  float d2 = 0.f;
  #pragma unroll
  for (int j = 0; j < 5; ++j){
    nom[j] = yv[j] + xy*ms[j];
    int c = lane + 64*j;
    float prd = nom[j]*nom[j];
    d2 += (c == 0) ? -prd : prd;
  }
  float den = sqrtf(fmaxf(wredf(d2), 1e-8f));
  float sc = dist / den;
  float u0 = __shfl(nom[0], 0, 64) * sc;
  float corr = -u0 / (1.f + m0);
  float var = scal[0] / (float)P;
  float g = gamma[0] / (var + 1e-5f);
  #pragma unroll
  for (int j = 0; j < 5; ++j){
    int c = lane + 64*j;
    uc[j] = (nom[j]*sc + corr*(ms[j] + ((c == 0) ? 1.f : 0.f))) * g;
  }
  float d3 = 0.f;
  #pragma unroll
  for (int j = 0; j < 5; ++j){
    int c = lane + 64*j;
    float prd = uc[j]*bs[j];
    d3 += (c == 0) ? -prd : prd;
  }
  float cb = wredf(d3) / (1.f + b0);
  float d4 = 0.f;
  #pragma unroll
  for (int j = 0; j < 5; ++j){
    int c = lane + 64*j;
    u2[j] = uc[j] + cb*(bs[j] + ((c == 0) ? 1.f : 0.f));
    float prd = u2[j]*u2[j];
    d4 += (c == 0) ? -prd : prd;
  }
  float nu = sqrtf(fmaxf(wredf(d4), 1e-8f));
  float ch = coshf(nu), shn = sinhf(nu) / nu;
  float ssum = 0.f;
  float* hp = hout + (size_t)p * C;
  #pragma unroll
  for (int j = 0; j < 5; ++j){
    int c = lane + 64*j;
    if (c > 0 && c < C){
      float r = ch*sbeta[c] + shn*u2[j];
      r = fmaxf(r, 0.f);
      hp[c] = r;
      ssum += r*r;
    }
  }
  ssum = wredf(ssum);
  if (lane == 0) hp[0] = sqrtf(ssum + 1.f);
}

// ---------------- flatten h4 (B,256,257) -> (B,65537) + square sums ---------
__global__ void flatten_kernel(const float* __restrict__ h, float* __restrict__ flat,
                               float* __restrict__ scal){
  __shared__ float s[256];
  int tid = threadIdx.x;
  int idx = blockIdx.x*256 + tid;
  int b = idx >> 16, r = idx & 65535;
  int n = r >> 8, c = r & 255;
  float v = h[(((size_t)b << 8) + n)*257 + 1 + c];
  flat[(size_t)b*65537 + 1 + r] = v;
  s[tid] = v*v; __syncthreads();
  for (int st = 128; st; st >>= 1){ if (tid < st) s[tid] += s[tid+st]; __syncthreads(); }
  if (tid == 0) atomicAdd(&scal[1 + b], s[0]);
}

__global__ void flat_time_kernel(float* __restrict__ flat, const float* __restrict__ scal){
  int b = threadIdx.x;
  if (b < 32) flat[(size_t)b*65537] = sqrtf(scal[1 + b] + 1.f);
}

// ---------------- head GEMM v2: k across lanes, coalesced W stream ----------
__global__ __launch_bounds__(256) void fgemm_kernel(const float* __restrict__ flat,
    const float* __restrict__ wm, const float* __restrict__ wv,
    float* __restrict__ mvacc){
  __shared__ float hlds[32*256];
  int tid = threadIdx.x;
  int wave = tid >> 6, l = tid & 63;
  int k0 = blockIdx.x * 4096;
  int obase = blockIdx.y * 16 + wave * 4;
  const float* rows[4];
  #pragma unroll
  for (int r = 0; r < 4; ++r){
    int o = obase + r;
    rows[r] = (o < 512) ? (wm + (size_t)(o + 1)*65537) : (wv + (size_t)(o - 511)*65537);
  }
  float acc[4][32] = {};
  for (int s = 0; s < 16; ++s){
    int kbase = k0 + s*256;
    #pragma unroll
    for (int b = 0; b < 32; ++b)
      hlds[b*256 + tid] = flat[(size_t)b*65537 + kbase + tid];
    __syncthreads();
    int kl = kbase + 4*l;
    float w0[4], w1[4], w2[4], w3[4];
    #pragma unroll
    for (int r = 0; r < 4; ++r){
      const float* wp = rows[r] + kl;
      w0[r] = wp[0]; w1[r] = wp[1]; w2[r] = wp[2]; w3[r] = wp[3];
    }
    #pragma unroll
    for (int b = 0; b < 32; ++b){
      float4 h4 = *(const float4*)&hlds[b*256 + 4*l];
      #pragma unroll
      for (int r = 0; r < 4; ++r){
        float t0 = fmaf(w0[r], h4.x, acc[r][b]);
        float t1 = fmaf(w1[r], h4.y, t0);
        float t2 = fmaf(w2[r], h4.z, t1);
        acc[r][b] = fmaf(w3[r], h4.w, t2);
      }
    }
    __syncthreads();
  }
  #pragma unroll
  for (int r = 0; r < 4; ++r){
    #pragma unroll
    for (int b = 0; b < 32; ++b){
      float v = wredf(acc[r][b]);
      if (l == 0) atomicAdd(&mvacc[(obase + r)*32 + b], v);
    }
  }
}

// ---------------- finalize: bias, k=65536 tail term, time, softplus ---------
__global__ void finalize_kernel(const float* __restrict__ mvacc, const float* __restrict__ bm,
                                const float* __restrict__ bv,
                                const float* __restrict__ wm, const float* __restrict__ wv,
                                const float* __restrict__ flat, float* __restrict__ out){
  __shared__ float s[256];
  int b = blockIdx.x, tid = threadIdx.x;
  float hl = flat[(size_t)b*65537 + 65536];
  float m0 = mvacc[tid*32 + b] + bm[tid + 1]
           + wm[(size_t)(tid + 1)*65537 + 65536] * hl;
  float m1 = mvacc[(tid + 256)*32 + b] + bm[tid + 257]
           + wm[(size_t)(tid + 257)*65537 + 65536] * hl;
  s[tid] = m0*m0 + m1*m1; __syncthreads();
  for (int st = 128; st; st >>= 1){ if (tid < st) s[tid] += s[tid+st]; __syncthreads(); }
  float t = sqrtf(s[0] + 1.f);
  float* om = out + (size_t)b*513;
  om[1 + tid] = m0;
  om[1 + tid + 256] = m1;
  if (tid == 0) om[0] = t;
  float v0 = mvacc[(512 + tid)*32 + b] + bv[tid + 1]
           + wv[(size_t)(tid + 1)*65537 + 65536] * hl;
  float v1 = mvacc[(512 + tid + 256)*32 + b] + bv[tid + 257]
           + wv[(size_t)(tid + 257)*65537 + 65536] * hl;
  float sp0 = fmaxf(v0, 0.f) + log1pf(expf(-fabsf(v0)));
  float sp1 = fmaxf(v1, 0.f) + log1pf(expf(-fabsf(v1)));
  float* ov = out + 32*513 + (size_t)b*512;
  ov[tid] = fmaxf(sp0, 1e-5f);
  ov[tid + 256] = fmaxf(sp1, 1e-5f);
}

extern "C" void kernel_launch(void* const* d_in, const int* in_sizes, int n_in,
                              void* d_out, int out_size, void* d_ws, size_t ws_size,
                              hipStream_t stream){
  const float* x  = (const float*)d_in[0];
  const float* cw[4] = {(const float*)d_in[1], (const float*)d_in[5], (const float*)d_in[9],  (const float*)d_in[13]};
  const float* cb[4] = {(const float*)d_in[2], (const float*)d_in[6], (const float*)d_in[10], (const float*)d_in[14]};
  const float* bb[4] = {(const float*)d_in[3], (const float*)d_in[7], (const float*)d_in[11], (const float*)d_in[15]};
  const float* bg[4] = {(const float*)d_in[4], (const float*)d_in[8], (const float*)d_in[12], (const float*)d_in[16]};
  const float* wm = (const float*)d_in[17];
  const float* bm = (const float*)d_in[18];
  const float* wv = (const float*)d_in[19];
  const float* bv = (const float*)d_in[20];
  float* ws = (float*)d_ws;

  // workspace layout (float offsets)
  unsigned short* h0bf = (unsigned short*)ws;              // 8.4M ushorts
  float* Y     = ws + 5000000;                             // <= 17.31M fp32
  unsigned short* Cbf = (unsigned short*)(ws + 23000000);  // <= 17.31M ushorts
  float* D     = ws + 32000000;                            // 2.11M fp32 (h4)
  float* flatp = ws + 35000000;                            // 2.10M fp32
  float* red2  = ws + 38000000;                            // <= 68k
  float* cent1 = ws + 38100000;                            // <= 32*257
  float* meanp = ws + 38110000;
  float* scal  = ws + 38111000;                            // [0]=var, [1..32]=flat sq
  float* mvacc = ws + 38112000;                            // 1024*32

  hipMemsetAsync(mvacc, 0, 32768*sizeof(float), stream);

  h0_kernel<<<8192, 256, 0, stream>>>(x, h0bf);

  const int HoA[4]   = {128, 64, 32, 16};
  const int CoutA[4] = {33, 65, 129, 257};
  const int BPBA[4]  = {64, 32, 16, 8};

  for (int i = 0; i < 4; ++i){
    int Ho = HoA[i], Cout = CoutA[i], BPB = BPBA[i];
    // conv (MFMA bf16)
    switch (i){
      case 0: conv_mfma_kernel<4,33,28,32><<<dim3(256,32,1), 256, 0, stream>>>(h0bf, cw[0], cb[0], Y, 256, 128); break;
      case 1: conv_mfma_kernel<33,65,289,64><<<dim3(64,32,1), 256, 0, stream>>>(Cbf, cw[1], cb[1], Y, 128, 64); break;
      case 2: conv_mfma_kernel<65,129,577,64><<<dim3(16,32,2), 256, 0, stream>>>(Cbf, cw[2], cb[2], Y, 64, 32); break;
      case 3: conv_mfma_kernel<129,257,1153,64><<<dim3(4,32,4), 256, 0, stream>>>(Cbf, cw[3], cb[3], Y, 32, 16); break;
    }
    int N = Ho * Ho;
    int P = 32 * N;
    int pb = P / 256;
    switch (i){
      case 0: time_t_kernel<33><<<pb, 256, 0, stream>>>(Y, P); break;
      case 1: time_t_kernel<65><<<pb, 256, 0, stream>>>(Y, P); break;
      case 2: time_t_kernel<129><<<pb, 256, 0, stream>>>(Y, P); break;
      case 3: time_t_kernel<257><<<pb, 256, 0, stream>>>(Y, P); break;
    }
    rsum_part_kernel<<<dim3(BPB, 32), 256, 0, stream>>>(Y, red2, N, Cout, BPB);
    cent1_kernel<<<32, 256, 0, stream>>>(red2, cent1, N, Cout, BPB);
    stats2_kernel<<<1, 256, 0, stream>>>(cent1, meanp, scal, Cout);
    int vb = min(pb, 2048);
    switch (i){
      case 0:
        bn_var_t_kernel<33><<<vb, 256, 0, stream>>>(Y, meanp, scal, P);
        bn_apply_bf_kernel<33><<<pb, 256, 0, stream>>>(Y, meanp, bb[i], bg[i], scal, Cbf, P);
        break;
      case 1:
        bn_var_t_kernel<65><<<vb, 256, 0, stream>>>(Y, meanp, scal, P);
        bn_apply_bf_kernel<65><<<pb, 256, 0, stream>>>(Y, meanp, bb[i], bg[i], scal, Cbf, P);
        break;
      case 2:
        bn_var_t_kernel<129><<<vb, 256, 0, stream>>>(Y, meanp, scal, P);
        bn_apply_bf_kernel<129><<<pb, 256, 0, stream>>>(Y, meanp, bb[i], bg[i], scal, Cbf, P);
        break;
      case 3:
        bn_var_kernel<<<min((P + 3)/4, 2048), 256, 0, stream>>>(Y, meanp, scal, P, Cout);
        bn_apply_kernel<<<(P + 3)/4, 256, 0, stream>>>(Y, meanp, bb[i], bg[i], scal, D, P, Cout);
        break;
    }
  }

  flatten_kernel<<<8192, 256, 0, stream>>>(D, flatp, scal);
  flat_time_kernel<<<1, 64, 0, stream>>>(flatp, scal);
  fgemm_kernel<<<dim3(16, 64), 256, 0, stream>>>(flatp, wm, wv, mvacc);
  finalize_kernel<<<32, 256, 0, stream>>>(mvacc, bm, bv, wm, wv, flatp, (float*)d_out);
}